// Round 2
// baseline (3073.774 us; speedup 1.0000x reference)
//
#include <hip/hip_runtime.h>

#define Bb 128
#define Tt 24
#define Ee 512
#define Hh 512
#define Aa 512
#define Vv 20000
#define Pp 196
#define TV (Tt*Vv)

typedef __attribute__((ext_vector_type(8))) short bfrag;           // 8 bf16 (4 VGPRs)
typedef __attribute__((ext_vector_type(4))) float f4;              // MFMA acc
typedef __attribute__((ext_vector_type(4))) unsigned short us4;    // 4 bf16 store

__device__ __forceinline__ unsigned short f2bf(float f){
  unsigned int x = __builtin_bit_cast(unsigned int, f);
  x += 0x7fffu + ((x >> 16) & 1u);   // RTNE
  return (unsigned short)(x >> 16);
}
__device__ __forceinline__ bfrag load8_bf(const unsigned short* p){ return *(const bfrag*)p; }
__device__ __forceinline__ bfrag load8_f32(const float* p){
  float4 a = *(const float4*)p; float4 b = *(const float4*)(p+4);
  bfrag r;
  r[0]=(short)f2bf(a.x); r[1]=(short)f2bf(a.y); r[2]=(short)f2bf(a.z); r[3]=(short)f2bf(a.w);
  r[4]=(short)f2bf(b.x); r[5]=(short)f2bf(b.y); r[6]=(short)f2bf(b.z); r[7]=(short)f2bf(b.w);
  return r;
}

// ---- elementwise f32 -> bf16 cast (grid-stride-free exact grids) ----
__global__ __launch_bounds__(256) void k_cast(const float* __restrict__ s,
                                              unsigned short* __restrict__ d, int n4){
  int i = blockIdx.x*256 + threadIdx.x;
  if(i >= n4) return;
  float4 v = ((const float4*)s)[i];
  us4 o; o[0]=f2bf(v.x); o[1]=f2bf(v.y); o[2]=f2bf(v.z); o[3]=f2bf(v.w);
  ((us4*)d)[i] = o;
}

// ---- 4x tiled 512x512 transpose f32 -> bf16 : D[a,e] = S[e,a] ----
__global__ __launch_bounds__(256) void k_tr(
    const float* __restrict__ W0, const float* __restrict__ W1,
    const float* __restrict__ W2, const float* __restrict__ W3,
    unsigned short* __restrict__ D0, unsigned short* __restrict__ D1,
    unsigned short* __restrict__ D2, unsigned short* __restrict__ D3){
  __shared__ float T[32][33];
  int z = blockIdx.z;
  const float* S = (z==0)?W0:(z==1)?W1:(z==2)?W2:W3;
  unsigned short* D = (z==0)?D0:(z==1)?D1:(z==2)?D2:D3;
  int it = blockIdx.x, jt = blockIdx.y;
  int t = threadIdx.x, er = t>>3, c4 = (t&7)*4;
  float4 v = *(const float4*)(S + (size_t)(jt*32+er)*512 + it*32 + c4);
  T[er][c4+0]=v.x; T[er][c4+1]=v.y; T[er][c4+2]=v.z; T[er][c4+3]=v.w;
  __syncthreads();
  us4 o;
  o[0]=f2bf(T[c4+0][er]); o[1]=f2bf(T[c4+1][er]);
  o[2]=f2bf(T[c4+2][er]); o[3]=f2bf(T[c4+3][er]);
  *(us4*)(D + (size_t)(it*32+er)*512 + jt*32 + c4) = o;
}

// ---- avg over P -> bf16 [B,E] ----
__global__ __launch_bounds__(256) void k_avg(const float* __restrict__ feats,
                                             unsigned short* __restrict__ avgB){
  int b = blockIdx.x, tid = threadIdx.x;
  const float* fb = feats + (size_t)b*Pp*Ee;
  float a0=0.f, a1=0.f;
  for(int p=0;p<Pp;p++){
    float2 v = *(const float2*)(fb + (size_t)p*Ee + tid*2);
    a0 += v.x; a1 += v.y;
  }
  a0 *= (1.0f/Pp); a1 *= (1.0f/Pp);
  unsigned int pack = ((unsigned int)f2bf(a1)<<16) | (unsigned int)f2bf(a0);
  ((unsigned int*)avgB)[(size_t)b*256 + tid] = pack;
}

// ---- init projections: tanh(avg @ W + b). grid (8, 2): y=0 -> h0, y=1 -> eseq[0] ----
__global__ __launch_bounds__(256) void k_initproj(
    const unsigned short* __restrict__ avgB,
    const unsigned short* __restrict__ WinhT, const unsigned short* __restrict__ WinoT,
    const float* __restrict__ binh, const float* __restrict__ bino,
    float* __restrict__ h0f, unsigned short* __restrict__ h0b,
    unsigned short* __restrict__ eseq){
  int tid = threadIdx.x, w = tid>>6, l = tid&63, l16 = l&15, lk = l>>4;
  int m0 = (w&1)*64, nb = blockIdx.x*64 + (w>>1)*32;
  int y = blockIdx.y;
  const unsigned short* Wt = y ? WinoT : WinhT;
  const float* bias = y ? bino : binh;
  f4 acc[4][2];
  #pragma unroll
  for(int mi=0;mi<4;mi++) for(int ni=0;ni<2;ni++) acc[mi][ni] = (f4)(0.0f);
  for(int k0=0;k0<512;k0+=32){
    int koff = k0 + lk*8;
    bfrag af[4], bq[2];
    #pragma unroll
    for(int mi=0;mi<4;mi++) af[mi] = load8_bf(avgB + (size_t)(m0+mi*16+l16)*512 + koff);
    #pragma unroll
    for(int ni=0;ni<2;ni++) bq[ni] = load8_bf(Wt + (size_t)(nb+ni*16+l16)*512 + koff);
    #pragma unroll
    for(int mi=0;mi<4;mi++)
      #pragma unroll
      for(int ni=0;ni<2;ni++)
        acc[mi][ni] = __builtin_amdgcn_mfma_f32_16x16x32_bf16(af[mi], bq[ni], acc[mi][ni], 0,0,0);
  }
  #pragma unroll
  for(int ni=0;ni<2;ni++){
    int n = nb + ni*16 + l16;
    float bv = bias[n];
    #pragma unroll
    for(int mi=0;mi<4;mi++){
      int bb = m0 + mi*16 + lk*4;
      #pragma unroll
      for(int i=0;i<4;i++){
        float val = tanhf(acc[mi][ni][i] + bv);
        if(y==0){ h0f[(size_t)(bb+i)*Hh + n] = val; h0b[(size_t)(bb+i)*Hh + n] = f2bf(val); }
        else     { eseq[(size_t)(bb+i)*Ee + n] = f2bf(val); }
      }
    }
  }
}

// ---- embedding gather f32 -> bf16, t = 1..23 ----
__global__ __launch_bounds__(256) void k_embed(const int* __restrict__ caps,
    const float* __restrict__ emb, unsigned short* __restrict__ eseq){
  int blk = blockIdx.x;
  int ts = blk / Bb + 1, b = blk % Bb;
  int cap = caps[b*Tt + (ts-1)];
  float2 v = *(const float2*)(emb + (size_t)cap*Ee + threadIdx.x*2);
  unsigned int pack = ((unsigned int)f2bf(v.y)<<16) | (unsigned int)f2bf(v.x);
  ((unsigned int*)(eseq + ((size_t)ts*Bb + b)*Ee))[threadIdx.x] = pack;
}

// ---- feat_proj = features @ Wf + bf -> bf16 [B*P, A]. grid (196, 8) ----
__global__ __launch_bounds__(256) void k_featproj(
    const float* __restrict__ featsF, const unsigned short* __restrict__ featsB,
    const unsigned short* __restrict__ WfT, const float* __restrict__ bfv,
    unsigned short* __restrict__ fpb){
  int tid = threadIdx.x, w = tid>>6, l = tid&63, l16 = l&15, lk = l>>4;
  size_t m_base = (size_t)blockIdx.x*128 + (w&1)*64;
  int nb = blockIdx.y*64 + (w>>1)*32;
  f4 acc[4][2];
  #pragma unroll
  for(int mi=0;mi<4;mi++) for(int ni=0;ni<2;ni++) acc[mi][ni] = (f4)(0.0f);
  for(int k0=0;k0<512;k0+=32){
    int koff = k0 + lk*8;
    bfrag af[4], bq[2];
    if(featsB){
      #pragma unroll
      for(int mi=0;mi<4;mi++) af[mi] = load8_bf(featsB + (m_base+mi*16+l16)*512 + koff);
    } else {
      #pragma unroll
      for(int mi=0;mi<4;mi++) af[mi] = load8_f32(featsF + (m_base+mi*16+l16)*512 + koff);
    }
    #pragma unroll
    for(int ni=0;ni<2;ni++) bq[ni] = load8_bf(WfT + (size_t)(nb+ni*16+l16)*512 + koff);
    #pragma unroll
    for(int mi=0;mi<4;mi++)
      #pragma unroll
      for(int ni=0;ni<2;ni++)
        acc[mi][ni] = __builtin_amdgcn_mfma_f32_16x16x32_bf16(af[mi], bq[ni], acc[mi][ni], 0,0,0);
  }
  #pragma unroll
  for(int ni=0;ni<2;ni++){
    int a = nb + ni*16 + l16;
    float bias = bfv[a];
    #pragma unroll
    for(int mi=0;mi<4;mi++){
      size_t r = m_base + mi*16 + lk*4;
      #pragma unroll
      for(int i=0;i<4;i++)
        fpb[(r+i)*512 + a] = f2bf(acc[mi][ni][i] + bias);
    }
  }
}

// ---- per-step: blocks 0..127 attention(t); blocks 128..440 pred(t-1) ----
__global__ __launch_bounds__(256) void k_step_fused(
    const float* __restrict__ featsF, const unsigned short* __restrict__ featsB,
    const unsigned short* __restrict__ fpb,
    const unsigned short* __restrict__ WhT, const float* __restrict__ bhv,
    const float* __restrict__ vatt,
    const unsigned short* __restrict__ WoutB, const float* __restrict__ WoutF,
    const float* __restrict__ bout,
    const float* __restrict__ h_cur, const unsigned short* __restrict__ hb_cur,
    unsigned short* __restrict__ ctxb, float* __restrict__ out, int t)
{
  __shared__ float h_s[Hh];
  __shared__ float hp[Aa];    // permuted: hp[(a&31)*16 + (a>>5)]
  __shared__ float vp[Aa];
  __shared__ float sc[Pp];
  __shared__ float red[2];

  int blk = blockIdx.x, tid = threadIdx.x;
  if(blk < 128){
    if(t >= Tt) return;
    int b = blk;
    { float2 hv = *(const float2*)(h_cur + (size_t)b*Hh + tid*2);
      h_s[tid*2] = hv.x; h_s[tid*2+1] = hv.y; }
    { float2 vv = *(const float2*)(vatt + tid*2);
      int a0 = tid*2, a1 = tid*2+1;
      vp[((a0&31)<<4) + (a0>>5)] = vv.x;
      vp[((a1&31)<<4) + (a1>>5)] = vv.y; }
    __syncthreads();
    // hproj[a] = bh[a] + sum_k h[k] * Wh[k,a]
    for(int rep=0;rep<2;rep++){
      int a = tid + rep*256;
      float s = bhv[a];
      const unsigned short* wr = WhT + (size_t)a*Hh;
      for(int k=0;k<Hh;k+=8){
        bfrag wv = *(const bfrag*)(wr + k);
        #pragma unroll
        for(int q=0;q<8;q++){
          unsigned int xb = ((unsigned int)(unsigned short)wv[q]) << 16;
          s += h_s[k+q] * __builtin_bit_cast(float, xb);
        }
      }
      hp[((a&31)<<4) + (a>>5)] = s;
    }
    __syncthreads();
    // scores
    int grp = tid >> 4, gl = tid & 15;
    for(int pass=0; pass<13; pass++){
      int p = pass*16 + grp;
      float acc = 0.0f;
      if(p < Pp){
        const unsigned short* fr = fpb + ((size_t)b*Pp + p)*Aa + gl*32;
        #pragma unroll
        for(int j=0;j<32;j+=8){
          bfrag fv = *(const bfrag*)(fr + j);
          #pragma unroll
          for(int q=0;q<8;q++){
            int idx = ((j+q)<<4) + gl;
            unsigned int xb = ((unsigned int)(unsigned short)fv[q]) << 16;
            float x = __builtin_bit_cast(float, xb) + hp[idx];
            acc += tanhf(x) * vp[idx];
          }
        }
      }
      acc += __shfl_xor(acc, 1, 64);
      acc += __shfl_xor(acc, 2, 64);
      acc += __shfl_xor(acc, 4, 64);
      acc += __shfl_xor(acc, 8, 64);
      if(p < Pp && gl == 0) sc[p] = acc;
    }
    __syncthreads();
    if(tid < 64){
      float m = -1e30f;
      for(int i=0;i<4;i++){ int p = tid + i*64; if(p < Pp) m = fmaxf(m, sc[p]); }
      for(int off=1; off<64; off<<=1) m = fmaxf(m, __shfl_xor(m, off, 64));
      float s = 0.0f;
      for(int i=0;i<4;i++){ int p = tid + i*64; if(p < Pp) s += expf(sc[p]-m); }
      for(int off=1; off<64; off<<=1) s += __shfl_xor(s, off, 64);
      if(tid == 0){ red[0] = m; red[1] = 1.0f/s; }
    }
    __syncthreads();
    float mx = red[0], rS = red[1];
    float al_t = 0.0f;
    if(tid < Pp) al_t = expf(sc[tid]-mx) * rS;
    __syncthreads();
    if(tid < Pp) sc[tid] = al_t;
    __syncthreads();
    float c0 = 0.f, c1 = 0.f;
    if(featsB){
      const unsigned int* fb = (const unsigned int*)(featsB + (size_t)b*Pp*Ee);
      for(int p=0;p<Pp;p++){
        float al = sc[p];
        unsigned int u = fb[(size_t)p*256 + tid];
        unsigned int lo = (u & 0xffffu) << 16, hi = u & 0xffff0000u;
        c0 += al * __builtin_bit_cast(float, lo);
        c1 += al * __builtin_bit_cast(float, hi);
      }
    } else {
      const float* fb = featsF + (size_t)b*Pp*Ee;
      for(int p=0;p<Pp;p++){
        float al = sc[p];
        float2 v = *(const float2*)(fb + (size_t)p*Ee + tid*2);
        c0 += al * v.x; c1 += al * v.y;
      }
    }
    unsigned int cw = ((unsigned int)f2bf(c1) << 16) | (unsigned int)f2bf(c0);
    ((unsigned int*)ctxb)[(size_t)b*256 + tid] = cw;
  } else {
    if(t == 0) return;
    int pb = blk - 128;
    int w = tid >> 6, l = tid & 63, l16 = l & 15, lk = l >> 4;
    int m0 = (w & 1)*64;
    int nb = pb*64 + (w >> 1)*32;
    f4 acc[4][2];
    #pragma unroll
    for(int mi=0;mi<4;mi++) for(int ni=0;ni<2;ni++) acc[mi][ni] = (f4)(0.0f);
    for(int k0=0;k0<512;k0+=32){
      int koff = k0 + lk*8;
      bfrag af[4], bq[2];
      #pragma unroll
      for(int mi=0;mi<4;mi++)
        af[mi] = load8_bf(hb_cur + (size_t)(m0 + mi*16 + l16)*Hh + koff);
      if(WoutB){
        #pragma unroll
        for(int ni=0;ni<2;ni++){
          int v = nb + ni*16 + l16; if(v > Vv-1) v = Vv-1;
          bq[ni] = load8_bf(WoutB + (size_t)v*Hh + koff);
        }
      } else {
        #pragma unroll
        for(int ni=0;ni<2;ni++){
          int v = nb + ni*16 + l16; if(v > Vv-1) v = Vv-1;
          bq[ni] = load8_f32(WoutF + (size_t)v*Hh + koff);
        }
      }
      #pragma unroll
      for(int mi=0;mi<4;mi++)
        #pragma unroll
        for(int ni=0;ni<2;ni++)
          acc[mi][ni] = __builtin_amdgcn_mfma_f32_16x16x32_bf16(af[mi], bq[ni], acc[mi][ni], 0,0,0);
    }
    #pragma unroll
    for(int ni=0;ni<2;ni++){
      int v = nb + ni*16 + l16;
      if(v < Vv){
        float bias = bout[v];
        #pragma unroll
        for(int mi=0;mi<4;mi++){
          int bb2 = m0 + mi*16 + lk*4;
          #pragma unroll
          for(int i=0;i<4;i++)
            out[(size_t)(bb2+i)*TV + (size_t)(t-1)*Vv + v] = acc[mi][ni][i] + bias;
        }
      }
    }
  }
}

// ---- GRU gates + h_new. grid 32, block 256 ----
__global__ __launch_bounds__(256) void k_gates(
    const unsigned short* __restrict__ eseq, const unsigned short* __restrict__ ctxb,
    const unsigned short* __restrict__ WihB, const unsigned short* __restrict__ WhhB,
    const float* __restrict__ bih, const float* __restrict__ bhh,
    const float* __restrict__ h_cur, const unsigned short* __restrict__ hb_cur,
    float* __restrict__ h_nxt, unsigned short* __restrict__ hb_nxt, int t)
{
  int tid = threadIdx.x;
  int w = tid >> 6, l = tid & 63, l16 = l & 15, lk = l >> 4;
  int hs = blockIdx.x*16 + l16;
  int m0 = w*32;
  const unsigned short* aemb = eseq + (size_t)t*Bb*Ee;
  f4 agi[2][3], agh[2][3];
  #pragma unroll
  for(int mi=0;mi<2;mi++) for(int g=0;g<3;g++){ agi[mi][g] = (f4)(0.0f); agh[mi][g] = (f4)(0.0f); }
  for(int k0=0;k0<512;k0+=32){
    int koff = k0 + lk*8;
    bfrag ah[2], ae[2], ac[2];
    #pragma unroll
    for(int mi=0;mi<2;mi++){
      int row = m0 + mi*16 + l16;
      ah[mi] = load8_bf(hb_cur + (size_t)row*Hh + koff);
      ae[mi] = load8_bf(aemb  + (size_t)row*Ee + koff);
      ac[mi] = load8_bf(ctxb  + (size_t)row*Ee + koff);
    }
    #pragma unroll
    for(int g=0;g<3;g++){
      int j = g*512 + hs;
      bfrag bh_ = load8_bf(WhhB + (size_t)j*512  + koff);
      bfrag be  = load8_bf(WihB + (size_t)j*1024 + koff);
      bfrag bc  = load8_bf(WihB + (size_t)j*1024 + 512 + koff);
      #pragma unroll
      for(int mi=0;mi<2;mi++){
        agh[mi][g] = __builtin_amdgcn_mfma_f32_16x16x32_bf16(ah[mi], bh_, agh[mi][g], 0,0,0);
        agi[mi][g] = __builtin_amdgcn_mfma_f32_16x16x32_bf16(ae[mi], be,  agi[mi][g], 0,0,0);
        agi[mi][g] = __builtin_amdgcn_mfma_f32_16x16x32_bf16(ac[mi], bc,  agi[mi][g], 0,0,0);
      }
    }
  }
  float bir = bih[hs],      bhr = bhh[hs];
  float biz = bih[512+hs],  bhz = bhh[512+hs];
  float bin = bih[1024+hs], bhn = bhh[1024+hs];
  #pragma unroll
  for(int mi=0;mi<2;mi++){
    #pragma unroll
    for(int i=0;i<4;i++){
      int b = m0 + mi*16 + lk*4 + i;
      float r = 1.0f/(1.0f + expf(-(agi[mi][0][i] + bir + agh[mi][0][i] + bhr)));
      float z = 1.0f/(1.0f + expf(-(agi[mi][1][i] + biz + agh[mi][1][i] + bhz)));
      float n = tanhf(agi[mi][2][i] + bin + r*(agh[mi][2][i] + bhn));
      float ho = h_cur[(size_t)b*Hh + hs];
      float hn = (1.0f - z)*n + z*ho;
      h_nxt [(size_t)b*Hh + hs] = hn;
      hb_nxt[(size_t)b*Hh + hs] = f2bf(hn);
    }
  }
}

extern "C" void kernel_launch(void* const* d_in, const int* in_sizes, int n_in,
                              void* d_out, int out_size, void* d_ws, size_t ws_size,
                              hipStream_t stream)
{
  const float* feats = (const float*)d_in[0];
  const int*   caps  = (const int*)d_in[1];
  const float* emb   = (const float*)d_in[2];
  const float* Winh  = (const float*)d_in[3];
  const float* binh  = (const float*)d_in[4];
  const float* Wino  = (const float*)d_in[5];
  const float* bino  = (const float*)d_in[6];
  const float* Wf    = (const float*)d_in[7];
  const float* bfv   = (const float*)d_in[8];
  const float* Wh    = (const float*)d_in[9];
  const float* bhv   = (const float*)d_in[10];
  const float* vatt  = (const float*)d_in[11];
  const float* Wih   = (const float*)d_in[12];
  const float* Whh   = (const float*)d_in[13];
  const float* bih   = (const float*)d_in[14];
  const float* bhh   = (const float*)d_in[15];
  const float* Wout  = (const float*)d_in[16];
  const float* bout  = (const float*)d_in[17];
  float* out = (float*)d_out;

  char* ws = (char*)d_ws;
  size_t off = 0;
  auto alloc = [&](size_t bytes){ void* p = ws + off; off += bytes; return p; };
  float* h_f[2]; unsigned short* h_b[2];
  h_f[0] = (float*)alloc((size_t)Bb*Hh*4);
  h_f[1] = (float*)alloc((size_t)Bb*Hh*4);
  h_b[0] = (unsigned short*)alloc((size_t)Bb*Hh*2);
  h_b[1] = (unsigned short*)alloc((size_t)Bb*Hh*2);
  unsigned short* ctxb  = (unsigned short*)alloc((size_t)Bb*Ee*2);
  unsigned short* avgB  = (unsigned short*)alloc((size_t)Bb*Ee*2);
  unsigned short* eseq  = (unsigned short*)alloc((size_t)Tt*Bb*Ee*2);
  unsigned short* WfT   = (unsigned short*)alloc((size_t)Ee*Aa*2);
  unsigned short* WhT   = (unsigned short*)alloc((size_t)Hh*Aa*2);
  unsigned short* WinhT = (unsigned short*)alloc((size_t)Ee*Hh*2);
  unsigned short* WinoT = (unsigned short*)alloc((size_t)Ee*Hh*2);
  unsigned short* WihB  = (unsigned short*)alloc((size_t)3*Hh*2*Ee*2);
  unsigned short* WhhB  = (unsigned short*)alloc((size_t)3*Hh*Hh*2);
  unsigned short* fpb   = (unsigned short*)alloc((size_t)Bb*Pp*Aa*2);
  size_t core_need = off;
  unsigned short* featsB = (unsigned short*)(ws + off);
  size_t featsB_need = off + (size_t)Bb*Pp*Ee*2;
  unsigned short* WoutB = (unsigned short*)(ws + featsB_need);
  size_t woutB_need = featsB_need + (size_t)Vv*Hh*2;

  if(ws_size < core_need) return;                    // diagnostic no-op
  bool haveFB = ws_size >= featsB_need;
  bool haveWB = ws_size >= woutB_need;
  const unsigned short* fBp = haveFB ? featsB : nullptr;
  const unsigned short* wBp = haveWB ? WoutB  : nullptr;

  // one-time prep
  k_cast<<<1536, 256, 0, stream>>>(Wih, WihB, 3*Hh*2*Ee/4);
  k_cast<<<768,  256, 0, stream>>>(Whh, WhhB, 3*Hh*Hh/4);
  if(haveFB) k_cast<<<12544, 256, 0, stream>>>(feats, featsB, Bb*Pp*Ee/4);
  if(haveWB) k_cast<<<10000, 256, 0, stream>>>(Wout, WoutB, Vv*Hh/4);
  k_tr<<<dim3(16,16,4), 256, 0, stream>>>(Wf, Wh, Winh, Wino, WfT, WhT, WinhT, WinoT);
  k_avg<<<128, 256, 0, stream>>>(feats, avgB);
  k_initproj<<<dim3(8,2), 256, 0, stream>>>(avgB, WinhT, WinoT, binh, bino,
                                            h_f[0], h_b[0], eseq);
  k_embed<<<(Tt-1)*Bb, 256, 0, stream>>>(caps, emb, eseq);
  k_featproj<<<dim3(196,8), 256, 0, stream>>>(feats, fBp, WfT, bfv, fpb);

  for(int t = 0; t <= Tt; t++){
    int cur = t & 1, nxt = (t + 1) & 1;
    k_step_fused<<<441, 256, 0, stream>>>(feats, fBp, fpb, WhT, bhv, vatt,
                                          wBp, Wout, bout,
                                          h_f[cur], h_b[cur], ctxb, out, t);
    if(t < Tt)
      k_gates<<<32, 256, 0, stream>>>(eseq, ctxb, WihB, WhhB, bih, bhh,
                                      h_f[cur], h_b[cur], h_f[nxt], h_b[nxt], t);
  }
}

// Round 3
// 2796.567 us; speedup vs baseline: 1.0991x; 1.0991x over previous
//
#include <hip/hip_runtime.h>

#define Bb 128
#define Tt 24
#define Ee 512
#define Hh 512
#define Aa 512
#define Vv 20000
#define Pp 196
#define TV (Tt*Vv)
#define NBLK 512
#define NTHR 256
#define GT (NBLK*NTHR)

typedef __attribute__((ext_vector_type(8))) short bfrag;           // 8 bf16
typedef __attribute__((ext_vector_type(4))) float f4;              // MFMA acc
typedef __attribute__((ext_vector_type(4))) unsigned short us4;    // 4 bf16

__device__ __forceinline__ unsigned short f2bf(float f){
  unsigned int x = __builtin_bit_cast(unsigned int, f);
  x += 0x7fffu + ((x >> 16) & 1u);   // RTNE
  return (unsigned short)(x >> 16);
}
__device__ __forceinline__ float bfu2f(unsigned short u){
  unsigned int x = ((unsigned int)u) << 16;
  return __builtin_bit_cast(float, x);
}
#define LOG2E 1.442695041f
__device__ __forceinline__ float fexp2(float x){ return __builtin_amdgcn_exp2f(x); }
__device__ __forceinline__ float frcp (float x){ return __builtin_amdgcn_rcpf(x); }
__device__ __forceinline__ float tanh_f(float x){ return 1.0f - 2.0f*frcp(1.0f + fexp2((2.0f*LOG2E)*x)); }
__device__ __forceinline__ float sigm_f(float x){ return frcp(1.0f + fexp2(-LOG2E*x)); }

// ---------------- grid barrier (agent scope) ----------------
__device__ __forceinline__ void gbar(unsigned* cnt, unsigned* gen){
  __syncthreads();
  if(threadIdx.x == 0){
    unsigned g = __hip_atomic_load(gen, __ATOMIC_RELAXED, __HIP_MEMORY_SCOPE_AGENT);
    unsigned a = __hip_atomic_fetch_add(cnt, 1u, __ATOMIC_ACQ_REL, __HIP_MEMORY_SCOPE_AGENT);
    if(a == (unsigned)(NBLK-1)){
      __hip_atomic_store(cnt, 0u, __ATOMIC_RELAXED, __HIP_MEMORY_SCOPE_AGENT);
      __hip_atomic_fetch_add(gen, 1u, __ATOMIC_ACQ_REL, __HIP_MEMORY_SCOPE_AGENT);
    } else {
      unsigned cur;
      do {
        __builtin_amdgcn_s_sleep(4);
        cur = __hip_atomic_load(gen, __ATOMIC_RELAXED, __HIP_MEMORY_SCOPE_AGENT);
      } while(cur == g);
      (void)__hip_atomic_load(gen, __ATOMIC_ACQUIRE, __HIP_MEMORY_SCOPE_AGENT); // acquire fence
    }
  }
  __syncthreads();
}

__global__ void k_zero(unsigned* bar){ if(threadIdx.x < 64) bar[threadIdx.x] = 0u; }

// ---------------- device phase helpers ----------------

__device__ __forceinline__ void cast_loop(const float* __restrict__ s,
                                          unsigned short* __restrict__ d,
                                          int n4, int gtid){
  for(int i = gtid; i < n4; i += GT){
    float4 v = ((const float4*)s)[i];
    us4 o; o[0]=f2bf(v.x); o[1]=f2bf(v.y); o[2]=f2bf(v.z); o[3]=f2bf(v.w);
    ((us4*)d)[i] = o;
  }
}

// 32x32 transpose tile task: D[a,e] = S[e,a] (f32 -> bf16), 512x512 matrices
__device__ __forceinline__ void tr_tile(const float* __restrict__ S,
                                        unsigned short* __restrict__ D,
                                        int it, int jt, int tid, float (*T)[33]){
  int er = tid>>3, c4 = (tid&7)*4;
  float4 v = *(const float4*)(S + (size_t)(jt*32+er)*512 + it*32 + c4);
  T[er][c4+0]=v.x; T[er][c4+1]=v.y; T[er][c4+2]=v.z; T[er][c4+3]=v.w;
  __syncthreads();
  us4 o;
  o[0]=f2bf(T[c4+0][er]); o[1]=f2bf(T[c4+1][er]);
  o[2]=f2bf(T[c4+2][er]); o[3]=f2bf(T[c4+3][er]);
  *(us4*)(D + (size_t)(it*32+er)*512 + jt*32 + c4) = o;
  __syncthreads();
}

// MFMA tile: rows of Abf (K=512 contig) x rows of Bt (K=512 contig); 128x64 out per task
// epilogue via callback-ish inline usage; here specialized twice below.

struct StepPtrs {
  const float* feats; const unsigned short* featsB; const unsigned short* fpb;
  const unsigned short* WhT; const float* bhv; const float* vatt;
  const unsigned short* WoutB; const float* bout;
  const unsigned short* WihB; const unsigned short* WhhB;
  const float* bih; const float* bhh;
  const unsigned short* eseq; unsigned short* ctxb;
  float* out;
};

__device__ void attention_task(int b, int t, const StepPtrs& P,
                               const float* __restrict__ h_cur){
  __shared__ float h_s[Hh];
  __shared__ float hp[Aa];    // permuted: hp[(a&31)*16 + (a>>5)]
  __shared__ float vp[Aa];
  __shared__ float sc[Pp];
  __shared__ float red[2];
  int tid = threadIdx.x;
  { float2 hv = *(const float2*)(h_cur + (size_t)b*Hh + tid*2);
    h_s[tid*2] = hv.x; h_s[tid*2+1] = hv.y; }
  { float2 vv = *(const float2*)(P.vatt + tid*2);
    int a0 = tid*2, a1 = tid*2+1;
    vp[((a0&31)<<4) + (a0>>5)] = vv.x;
    vp[((a1&31)<<4) + (a1>>5)] = vv.y; }
  __syncthreads();
  // hproj[a] = bh[a] + sum_k h[k] * Wh[k,a]
  for(int rep=0;rep<2;rep++){
    int a = tid + rep*256;
    float s = P.bhv[a];
    const unsigned short* wr = P.WhT + (size_t)a*Hh;
    for(int k=0;k<Hh;k+=8){
      bfrag wv = *(const bfrag*)(wr + k);
      #pragma unroll
      for(int q=0;q<8;q++) s += h_s[k+q] * bfu2f((unsigned short)wv[q]);
    }
    hp[((a&31)<<4) + (a>>5)] = s;
  }
  __syncthreads();
  // scores
  int grp = tid >> 4, gl = tid & 15;
  for(int pass=0; pass<13; pass++){
    int p = pass*16 + grp;
    float acc = 0.0f;
    if(p < Pp){
      const unsigned short* fr = P.fpb + ((size_t)b*Pp + p)*Aa + gl*32;
      #pragma unroll
      for(int j=0;j<32;j+=8){
        bfrag fv = *(const bfrag*)(fr + j);
        #pragma unroll
        for(int q=0;q<8;q++){
          int idx = ((j+q)<<4) + gl;
          float x = bfu2f((unsigned short)fv[q]) + hp[idx];
          acc += tanh_f(x) * vp[idx];
        }
      }
    }
    acc += __shfl_xor(acc, 1, 64);
    acc += __shfl_xor(acc, 2, 64);
    acc += __shfl_xor(acc, 4, 64);
    acc += __shfl_xor(acc, 8, 64);
    if(p < Pp && gl == 0) sc[p] = acc;
  }
  __syncthreads();
  if(tid < 64){
    float m = -1e30f;
    for(int i=0;i<4;i++){ int p = tid + i*64; if(p < Pp) m = fmaxf(m, sc[p]); }
    for(int off=1; off<64; off<<=1) m = fmaxf(m, __shfl_xor(m, off, 64));
    float s = 0.0f;
    for(int i=0;i<4;i++){ int p = tid + i*64; if(p < Pp) s += fexp2((sc[p]-m)*LOG2E); }
    for(int off=1; off<64; off<<=1) s += __shfl_xor(s, off, 64);
    if(tid == 0){ red[0] = m; red[1] = frcp(s); }
  }
  __syncthreads();
  float mx = red[0], rS = red[1];
  float al_t = 0.0f;
  if(tid < Pp) al_t = fexp2((sc[tid]-mx)*LOG2E) * rS;
  __syncthreads();
  if(tid < Pp) sc[tid] = al_t;
  __syncthreads();
  float c0 = 0.f, c1 = 0.f;
  const unsigned int* fb = (const unsigned int*)(P.featsB + (size_t)b*Pp*Ee);
  for(int p=0;p<Pp;p++){
    float al = sc[p];
    unsigned int u = fb[(size_t)p*256 + tid];
    unsigned int lo = (u & 0xffffu) << 16, hi = u & 0xffff0000u;
    c0 += al * __builtin_bit_cast(float, lo);
    c1 += al * __builtin_bit_cast(float, hi);
  }
  unsigned int cw = ((unsigned int)f2bf(c1) << 16) | (unsigned int)f2bf(c0);
  ((unsigned int*)P.ctxb)[(size_t)b*256 + tid] = cw;
}

__device__ void pred_task(int pt, int tw, const StepPtrs& P,
                          const unsigned short* __restrict__ hb_cur){
  int tid = threadIdx.x;
  int w = tid >> 6, l = tid & 63, l16 = l & 15, lk = l >> 4;
  int m0 = (w & 1)*64;
  int nb = pt*64 + (w >> 1)*32;
  f4 acc[4][2];
  #pragma unroll
  for(int mi=0;mi<4;mi++) for(int ni=0;ni<2;ni++) acc[mi][ni] = (f4)(0.0f);
  for(int k0=0;k0<512;k0+=32){
    int koff = k0 + lk*8;
    bfrag af[4], bq[2];
    #pragma unroll
    for(int mi=0;mi<4;mi++)
      af[mi] = *(const bfrag*)(hb_cur + (size_t)(m0 + mi*16 + l16)*Hh + koff);
    #pragma unroll
    for(int ni=0;ni<2;ni++){
      int v = nb + ni*16 + l16; if(v > Vv-1) v = Vv-1;
      bq[ni] = *(const bfrag*)(P.WoutB + (size_t)v*Hh + koff);
    }
    #pragma unroll
    for(int mi=0;mi<4;mi++)
      #pragma unroll
      for(int ni=0;ni<2;ni++)
        acc[mi][ni] = __builtin_amdgcn_mfma_f32_16x16x32_bf16(af[mi], bq[ni], acc[mi][ni], 0,0,0);
  }
  #pragma unroll
  for(int ni=0;ni<2;ni++){
    int v = nb + ni*16 + l16;
    if(v < Vv){
      float bias = P.bout[v];
      #pragma unroll
      for(int mi=0;mi<4;mi++){
        int bb2 = m0 + mi*16 + lk*4;
        #pragma unroll
        for(int i=0;i<4;i++)
          __builtin_nontemporal_store(acc[mi][ni][i] + bias,
              P.out + (size_t)(bb2+i)*TV + (size_t)tw*Vv + v);
      }
    }
  }
}

__device__ void gates_task(int task, int t, const StepPtrs& P,
                           const float* __restrict__ h_cur,
                           const unsigned short* __restrict__ hb_cur,
                           float* __restrict__ h_nxt,
                           unsigned short* __restrict__ hb_nxt){
  int tid = threadIdx.x;
  int w = tid >> 6, l = tid & 63, l16 = l & 15, lk = l >> 4;
  int hs = task*16 + l16;
  int m0 = w*32;
  const unsigned short* aemb = P.eseq + (size_t)t*Bb*Ee;
  f4 agi[2][3], agh[2][3];
  #pragma unroll
  for(int mi=0;mi<2;mi++) for(int g=0;g<3;g++){ agi[mi][g] = (f4)(0.0f); agh[mi][g] = (f4)(0.0f); }
  for(int k0=0;k0<512;k0+=32){
    int koff = k0 + lk*8;
    bfrag ah[2], ae[2], ac[2];
    #pragma unroll
    for(int mi=0;mi<2;mi++){
      int row = m0 + mi*16 + l16;
      ah[mi] = *(const bfrag*)(hb_cur + (size_t)row*Hh + koff);
      ae[mi] = *(const bfrag*)(aemb   + (size_t)row*Ee + koff);
      ac[mi] = *(const bfrag*)(P.ctxb + (size_t)row*Ee + koff);
    }
    #pragma unroll
    for(int g=0;g<3;g++){
      int j = g*512 + hs;
      bfrag bh_ = *(const bfrag*)(P.WhhB + (size_t)j*512  + koff);
      bfrag be  = *(const bfrag*)(P.WihB + (size_t)j*1024 + koff);
      bfrag bc  = *(const bfrag*)(P.WihB + (size_t)j*1024 + 512 + koff);
      #pragma unroll
      for(int mi=0;mi<2;mi++){
        agh[mi][g] = __builtin_amdgcn_mfma_f32_16x16x32_bf16(ah[mi], bh_, agh[mi][g], 0,0,0);
        agi[mi][g] = __builtin_amdgcn_mfma_f32_16x16x32_bf16(ae[mi], be,  agi[mi][g], 0,0,0);
        agi[mi][g] = __builtin_amdgcn_mfma_f32_16x16x32_bf16(ac[mi], bc,  agi[mi][g], 0,0,0);
      }
    }
  }
  float bir = P.bih[hs],      bhr = P.bhh[hs];
  float biz = P.bih[512+hs],  bhz = P.bhh[512+hs];
  float bin = P.bih[1024+hs], bhn = P.bhh[1024+hs];
  #pragma unroll
  for(int mi=0;mi<2;mi++){
    #pragma unroll
    for(int i=0;i<4;i++){
      int b = m0 + mi*16 + lk*4 + i;
      float r = sigm_f(agi[mi][0][i] + bir + agh[mi][0][i] + bhr);
      float z = sigm_f(agi[mi][1][i] + biz + agh[mi][1][i] + bhz);
      float n = tanh_f(agi[mi][2][i] + bin + r*(agh[mi][2][i] + bhn));
      float ho = h_cur[(size_t)b*Hh + hs];
      float hn = (1.0f - z)*n + z*ho;
      h_nxt [(size_t)b*Hh + hs] = hn;
      hb_nxt[(size_t)b*Hh + hs] = f2bf(hn);
    }
  }
}

// ---------------- the persistent kernel ----------------
__global__ __launch_bounds__(NTHR, 2) void k_all(
    const float* feats, const int* caps, const float* emb,
    const float* Winh, const float* binh, const float* Wino, const float* bino,
    const float* Wf, const float* bfv, const float* Wh, const float* bhv,
    const float* vatt, const float* Wih, const float* Whh,
    const float* bih, const float* bhh, const float* Wout, const float* bout,
    float* out,
    float* h_f0, float* h_f1, unsigned short* h_b0, unsigned short* h_b1,
    unsigned short* ctxb, unsigned short* avgB, unsigned short* eseq,
    unsigned short* WfT, unsigned short* WhT,
    unsigned short* WinhT, unsigned short* WinoT,
    unsigned short* WihB, unsigned short* WhhB,
    unsigned short* fpb, unsigned short* featsB, unsigned short* WoutB,
    unsigned* bar)
{
  const int blk = blockIdx.x, tid = threadIdx.x;
  const int gtid = blk*NTHR + tid;
  unsigned* cnt = &bar[0];
  unsigned* gen = &bar[32];
  __shared__ float T[32][33];

  // ================= P0: casts, transposes, avg, embed =================
  cast_loop(Wih,  WihB,  (3*Hh*2*Ee)/4, gtid);
  cast_loop(Whh,  WhhB,  (3*Hh*Hh)/4,   gtid);
  cast_loop(Wout, WoutB, (Vv*Hh)/4,     gtid);
  cast_loop(feats,featsB,(Bb*Pp*Ee)/4,  gtid);
  // 4 matrices x 256 tiles each
  for(int task = blk; task < 1024; task += NBLK){
    int z = task >> 8, rt = task & 255;
    int it = rt & 15, jt = rt >> 4;
    const float* S = (z==0)?Wf:(z==1)?Wh:(z==2)?Winh:Wino;
    unsigned short* D = (z==0)?WfT:(z==1)?WhT:(z==2)?WinhT:WinoT;
    tr_tile(S, D, it, jt, tid, T);
  }
  if(blk < Bb){
    int b = blk;
    const float* fb = feats + (size_t)b*Pp*Ee;
    float a0=0.f, a1=0.f;
    for(int p=0;p<Pp;p++){
      float2 v = *(const float2*)(fb + (size_t)p*Ee + tid*2);
      a0 += v.x; a1 += v.y;
    }
    a0 *= (1.0f/Pp); a1 *= (1.0f/Pp);
    unsigned int pack = ((unsigned int)f2bf(a1)<<16) | (unsigned int)f2bf(a0);
    ((unsigned int*)avgB)[(size_t)b*256 + tid] = pack;
  }
  for(int task = blk; task < (Tt-1)*Bb; task += NBLK){
    int ts = task/Bb + 1, b = task%Bb;
    int cap = caps[b*Tt + (ts-1)];
    float2 v = *(const float2*)(emb + (size_t)cap*Ee + tid*2);
    unsigned int pack = ((unsigned int)f2bf(v.y)<<16) | (unsigned int)f2bf(v.x);
    ((unsigned int*)(eseq + ((size_t)ts*Bb + b)*Ee))[tid] = pack;
  }
  gbar(cnt, gen);

  // ================= P1: featproj (1568) + initproj (16) =================
  for(int task = blk; task < 1584; task += NBLK){
    int w = tid>>6, l = tid&63, l16 = l&15, lk = l>>4;
    if(task < 1568){
      int bx = task % 196, by = task / 196;
      size_t m_base = (size_t)bx*128 + (w&1)*64;
      int nb = by*64 + (w>>1)*32;
      f4 acc[4][2];
      #pragma unroll
      for(int mi=0;mi<4;mi++) for(int ni=0;ni<2;ni++) acc[mi][ni] = (f4)(0.0f);
      for(int k0=0;k0<512;k0+=32){
        int koff = k0 + lk*8;
        bfrag af[4], bq[2];
        #pragma unroll
        for(int mi=0;mi<4;mi++) af[mi] = *(const bfrag*)(featsB + (m_base+mi*16+l16)*512 + koff);
        #pragma unroll
        for(int ni=0;ni<2;ni++) bq[ni] = *(const bfrag*)(WfT + (size_t)(nb+ni*16+l16)*512 + koff);
        #pragma unroll
        for(int mi=0;mi<4;mi++)
          #pragma unroll
          for(int ni=0;ni<2;ni++)
            acc[mi][ni] = __builtin_amdgcn_mfma_f32_16x16x32_bf16(af[mi], bq[ni], acc[mi][ni], 0,0,0);
      }
      #pragma unroll
      for(int ni=0;ni<2;ni++){
        int a = nb + ni*16 + l16;
        float bias = bfv[a];
        #pragma unroll
        for(int mi=0;mi<4;mi++){
          size_t r = m_base + mi*16 + lk*4;
          #pragma unroll
          for(int i=0;i<4;i++)
            fpb[(r+i)*512 + a] = f2bf(acc[mi][ni][i] + bias);
        }
      }
    } else {
      int idx = task - 1568;
      int y = idx >> 3, xb = idx & 7;
      int m0 = (w&1)*64, nb = xb*64 + (w>>1)*32;
      const unsigned short* Wt = y ? WinoT : WinhT;
      const float* bias = y ? bino : binh;
      f4 acc[4][2];
      #pragma unroll
      for(int mi=0;mi<4;mi++) for(int ni=0;ni<2;ni++) acc[mi][ni] = (f4)(0.0f);
      for(int k0=0;k0<512;k0+=32){
        int koff = k0 + lk*8;
        bfrag af[4], bq[2];
        #pragma unroll
        for(int mi=0;mi<4;mi++) af[mi] = *(const bfrag*)(avgB + (size_t)(m0+mi*16+l16)*512 + koff);
        #pragma unroll
        for(int ni=0;ni<2;ni++) bq[ni] = *(const bfrag*)(Wt + (size_t)(nb+ni*16+l16)*512 + koff);
        #pragma unroll
        for(int mi=0;mi<4;mi++)
          #pragma unroll
          for(int ni=0;ni<2;ni++)
            acc[mi][ni] = __builtin_amdgcn_mfma_f32_16x16x32_bf16(af[mi], bq[ni], acc[mi][ni], 0,0,0);
      }
      #pragma unroll
      for(int ni=0;ni<2;ni++){
        int n = nb + ni*16 + l16;
        float bv = bias[n];
        #pragma unroll
        for(int mi=0;mi<4;mi++){
          int bb = m0 + mi*16 + lk*4;
          #pragma unroll
          for(int i=0;i<4;i++){
            float val = tanh_f(acc[mi][ni][i] + bv);
            if(y==0){ h_f0[(size_t)(bb+i)*Hh + n] = val; h_b0[(size_t)(bb+i)*Hh + n] = f2bf(val); }
            else    { eseq[(size_t)(bb+i)*Ee + n] = f2bf(val); }
          }
        }
      }
    }
  }
  gbar(cnt, gen);

  // ================= step loop =================
  StepPtrs P;
  P.feats = feats; P.featsB = featsB; P.fpb = fpb;
  P.WhT = WhT; P.bhv = bhv; P.vatt = vatt;
  P.WoutB = WoutB; P.bout = bout;
  P.WihB = WihB; P.WhhB = WhhB; P.bih = bih; P.bhh = bhh;
  P.eseq = eseq; P.ctxb = ctxb; P.out = out;

  for(int t = 0; t <= Tt; t++){
    float*          hf_cur = (t & 1) ? h_f1 : h_f0;
    unsigned short* hb_cur = (t & 1) ? h_b1 : h_b0;
    float*          hf_nxt = (t & 1) ? h_f0 : h_f1;
    unsigned short* hb_nxt = (t & 1) ? h_b0 : h_b1;
    if(blk < 128){
      if(t < Tt) attention_task(blk, t, P, hf_cur);
    } else if(t > 0){
      int pt = blk - 128;
      if(pt < 313) pred_task(pt, t-1, P, hb_cur);
    }
    gbar(cnt, gen);
    if(t < Tt){
      if(blk < 32) gates_task(blk, t, P, hf_cur, hb_cur, hf_nxt, hb_nxt);
      gbar(cnt, gen);
    }
  }
}

extern "C" void kernel_launch(void* const* d_in, const int* in_sizes, int n_in,
                              void* d_out, int out_size, void* d_ws, size_t ws_size,
                              hipStream_t stream)
{
  const float* feats = (const float*)d_in[0];
  const int*   caps  = (const int*)d_in[1];
  const float* emb   = (const float*)d_in[2];
  const float* Winh  = (const float*)d_in[3];
  const float* binh  = (const float*)d_in[4];
  const float* Wino  = (const float*)d_in[5];
  const float* bino  = (const float*)d_in[6];
  const float* Wf    = (const float*)d_in[7];
  const float* bfv   = (const float*)d_in[8];
  const float* Wh    = (const float*)d_in[9];
  const float* bhv   = (const float*)d_in[10];
  const float* vatt  = (const float*)d_in[11];
  const float* Wih   = (const float*)d_in[12];
  const float* Whh   = (const float*)d_in[13];
  const float* bih   = (const float*)d_in[14];
  const float* bhh   = (const float*)d_in[15];
  const float* Wout  = (const float*)d_in[16];
  const float* bout  = (const float*)d_in[17];
  float* out = (float*)d_out;

  char* ws = (char*)d_ws;
  size_t off = 0;
  auto alloc = [&](size_t bytes){
    off = (off + 255) & ~(size_t)255;
    void* p = ws + off; off += bytes; return p;
  };
  unsigned* bar = (unsigned*)alloc(256);
  float* h_f0 = (float*)alloc((size_t)Bb*Hh*4);
  float* h_f1 = (float*)alloc((size_t)Bb*Hh*4);
  unsigned short* h_b0 = (unsigned short*)alloc((size_t)Bb*Hh*2);
  unsigned short* h_b1 = (unsigned short*)alloc((size_t)Bb*Hh*2);
  unsigned short* ctxb  = (unsigned short*)alloc((size_t)Bb*Ee*2);
  unsigned short* avgB  = (unsigned short*)alloc((size_t)Bb*Ee*2);
  unsigned short* eseq  = (unsigned short*)alloc((size_t)Tt*Bb*Ee*2);
  unsigned short* WfT   = (unsigned short*)alloc((size_t)Ee*Aa*2);
  unsigned short* WhT   = (unsigned short*)alloc((size_t)Hh*Aa*2);
  unsigned short* WinhT = (unsigned short*)alloc((size_t)Ee*Hh*2);
  unsigned short* WinoT = (unsigned short*)alloc((size_t)Ee*Hh*2);
  unsigned short* WihB  = (unsigned short*)alloc((size_t)3*Hh*2*Ee*2);
  unsigned short* WhhB  = (unsigned short*)alloc((size_t)3*Hh*Hh*2);
  unsigned short* fpb   = (unsigned short*)alloc((size_t)Bb*Pp*Aa*2);
  unsigned short* featsB= (unsigned short*)alloc((size_t)Bb*Pp*Ee*2);
  unsigned short* WoutB = (unsigned short*)alloc((size_t)Vv*Hh*2);
  if(ws_size < off) return;   // diagnostic no-op (finite-absmax fail => ws too small)

  k_zero<<<1, 64, 0, stream>>>(bar);
  k_all<<<NBLK, NTHR, 0, stream>>>(
      feats, caps, emb, Winh, binh, Wino, bino, Wf, bfv, Wh, bhv, vatt,
      Wih, Whh, bih, bhh, Wout, bout, out,
      h_f0, h_f1, h_b0, h_b1, ctxb, avgB, eseq,
      WfT, WhT, WinhT, WinoT, WihB, WhhB, fpb, featsB, WoutB, bar);
}

// Round 5
// 2293.846 us; speedup vs baseline: 1.3400x; 1.2192x over previous
//
#include <hip/hip_runtime.h>

#define Bb 128
#define Tt 24
#define Ee 512
#define Hh 512
#define Aa 512
#define Vv 20000
#define Pp 196
#define TV (Tt*Vv)
#define NBLK 512
#define NTHR 256
#define GT (NBLK*NTHR)

// sync[] word indices (all zeroed by k_zero each launch)
#define SYNC_CNT 0
#define SYNC_GEN 16
#define CTXD 64      // +t   target 128  (attn -> gates)
#define HRDY 96      // +t   target 32   (gates1 -> gates2/pred)
#define HPRD 128     // +t   target 32   (gates2 -> attn)
#define PREDD 160    // +t   target 314  (pred -> gates1 WAR guard)

typedef __attribute__((ext_vector_type(8))) short bfrag;           // 8 bf16
typedef __attribute__((ext_vector_type(4))) float f4;              // MFMA acc
typedef __attribute__((ext_vector_type(4))) unsigned short us4;    // 4 bf16
typedef __attribute__((ext_vector_type(2))) unsigned long long u64x2;

__device__ __forceinline__ unsigned short f2bf(float f){
  unsigned int x = __builtin_bit_cast(unsigned int, f);
  x += 0x7fffu + ((x >> 16) & 1u);   // RTNE
  return (unsigned short)(x >> 16);
}
__device__ __forceinline__ float bfu2f(unsigned short u){
  unsigned int x = ((unsigned int)u) << 16;
  return __builtin_bit_cast(float, x);
}
#define LOG2E 1.442695041f
__device__ __forceinline__ float fexp2(float x){ return __builtin_amdgcn_exp2f(x); }
__device__ __forceinline__ float frcp (float x){ return __builtin_amdgcn_rcpf(x); }
__device__ __forceinline__ float tanh_f(float x){ return 1.0f - 2.0f*frcp(1.0f + fexp2((2.0f*LOG2E)*x)); }
__device__ __forceinline__ float sigm_f(float x){ return frcp(1.0f + fexp2(-LOG2E*x)); }

// ---- device-coherent access helpers (bypass non-coherent caching) ----
__device__ __forceinline__ unsigned long long scld8(const void* p){
  return __hip_atomic_load((const unsigned long long*)p, __ATOMIC_RELAXED, __HIP_MEMORY_SCOPE_AGENT);
}
__device__ __forceinline__ bfrag scld_frag(const unsigned short* p){
  u64x2 v;
  v.x = scld8(p);
  v.y = scld8(p + 4);
  return __builtin_bit_cast(bfrag, v);
}
__device__ __forceinline__ void scst4(unsigned* p, unsigned v){
  __hip_atomic_store(p, v, __ATOMIC_RELAXED, __HIP_MEMORY_SCOPE_AGENT);
}
__device__ __forceinline__ void scstf(float* p, float v){
  __hip_atomic_store(p, v, __ATOMIC_RELAXED, __HIP_MEMORY_SCOPE_AGENT);
}

// ---- counter sync: producer signal / consumer poll (no L2 inv/wb) ----
__device__ __forceinline__ void signal_ctr(unsigned* c){
  asm volatile("s_waitcnt vmcnt(0)" ::: "memory");   // coherent stores visible at L3
  __syncthreads();
  if(threadIdx.x == 0)
    (void)__hip_atomic_fetch_add(c, 1u, __ATOMIC_RELAXED, __HIP_MEMORY_SCOPE_AGENT);
}
__device__ __forceinline__ void wait_ctr(unsigned* c, unsigned tgt){
  if(threadIdx.x == 0){
    while(__hip_atomic_load(c, __ATOMIC_RELAXED, __HIP_MEMORY_SCOPE_AGENT) < tgt)
      __builtin_amdgcn_s_sleep(1);
  }
  __syncthreads();
  asm volatile("" ::: "memory");
}

// ---- grid barrier (prep only; acquire/release = L2 wb+inv, used twice) ----
__device__ __forceinline__ void gbar(unsigned* cnt, unsigned* gen){
  __syncthreads();
  if(threadIdx.x == 0){
    unsigned g = __hip_atomic_load(gen, __ATOMIC_RELAXED, __HIP_MEMORY_SCOPE_AGENT);
    unsigned a = __hip_atomic_fetch_add(cnt, 1u, __ATOMIC_ACQ_REL, __HIP_MEMORY_SCOPE_AGENT);
    if(a == (unsigned)(NBLK-1)){
      __hip_atomic_store(cnt, 0u, __ATOMIC_RELAXED, __HIP_MEMORY_SCOPE_AGENT);
      __hip_atomic_fetch_add(gen, 1u, __ATOMIC_ACQ_REL, __HIP_MEMORY_SCOPE_AGENT);
    } else {
      unsigned cur;
      do {
        __builtin_amdgcn_s_sleep(4);
        cur = __hip_atomic_load(gen, __ATOMIC_RELAXED, __HIP_MEMORY_SCOPE_AGENT);
      } while(cur == g);
      (void)__hip_atomic_load(gen, __ATOMIC_ACQUIRE, __HIP_MEMORY_SCOPE_AGENT);
    }
  }
  __syncthreads();
}

__global__ void k_zero(unsigned* s){ s[threadIdx.x] = 0u; }

// ---------------- prep helpers ----------------
__device__ __forceinline__ void cast_loop(const float* __restrict__ s,
                                          unsigned short* __restrict__ d,
                                          int n4, int gtid){
  for(int i = gtid; i < n4; i += GT){
    float4 v = ((const float4*)s)[i];
    us4 o; o[0]=f2bf(v.x); o[1]=f2bf(v.y); o[2]=f2bf(v.z); o[3]=f2bf(v.w);
    ((us4*)d)[i] = o;
  }
}
__device__ __forceinline__ void tr_tile(const float* __restrict__ S,
                                        unsigned short* __restrict__ D,
                                        int it, int jt, int tid, float (*T)[33]){
  int er = tid>>3, c4 = (tid&7)*4;
  float4 v = *(const float4*)(S + (size_t)(jt*32+er)*512 + it*32 + c4);
  T[er][c4+0]=v.x; T[er][c4+1]=v.y; T[er][c4+2]=v.z; T[er][c4+3]=v.w;
  __syncthreads();
  us4 o;
  o[0]=f2bf(T[c4+0][er]); o[1]=f2bf(T[c4+1][er]);
  o[2]=f2bf(T[c4+2][er]); o[3]=f2bf(T[c4+3][er]);
  *(us4*)(D + (size_t)(it*32+er)*512 + jt*32 + c4) = o;
  __syncthreads();
}

// ---------------- step-loop tasks ----------------

// attention for batch-row b (hproj precomputed in hpr, bias included)
__device__ void attention_task(int b, const float* __restrict__ hpr,
                               const unsigned short* __restrict__ fpb,
                               const unsigned short* __restrict__ featsB,
                               const float* __restrict__ vatt,
                               unsigned short* __restrict__ ctxb, char* SM)
{
  float* hp  = (float*)SM;        // 512, permuted hp[(a&31)*16 + (a>>5)]
  float* vp  = hp + 512;          // 512
  float* sc  = vp + 512;          // 196 (+pad)
  float* red = sc + 200;          // 2
  int tid = threadIdx.x;
  {
    unsigned long long q = scld8(hpr + (size_t)b*Aa + tid*2);
    float2 hv = __builtin_bit_cast(float2, q);
    float2 vv = *(const float2*)(vatt + tid*2);
    int a0 = tid*2, a1 = tid*2+1;
    hp[((a0&31)<<4)+(a0>>5)] = hv.x;
    hp[((a1&31)<<4)+(a1>>5)] = hv.y;
    vp[((a0&31)<<4)+(a0>>5)] = vv.x;
    vp[((a1&31)<<4)+(a1>>5)] = vv.y;
  }
  __syncthreads();
  int grp = tid >> 4, gl = tid & 15;
  for(int pass=0; pass<13; pass++){
    int p = pass*16 + grp;
    float acc = 0.0f;
    if(p < Pp){
      const unsigned short* fr = fpb + ((size_t)b*Pp + p)*Aa + gl*32;
      #pragma unroll
      for(int j=0;j<32;j+=8){
        bfrag fv = *(const bfrag*)(fr + j);
        #pragma unroll
        for(int q=0;q<8;q++){
          int idx = ((j+q)<<4) + gl;
          float x = bfu2f((unsigned short)fv[q]) + hp[idx];
          acc += tanh_f(x) * vp[idx];
        }
      }
    }
    acc += __shfl_xor(acc, 1, 64);
    acc += __shfl_xor(acc, 2, 64);
    acc += __shfl_xor(acc, 4, 64);
    acc += __shfl_xor(acc, 8, 64);
    if(p < Pp && gl == 0) sc[p] = acc;
  }
  __syncthreads();
  if(tid < 64){
    float m = -1e30f;
    for(int i=0;i<4;i++){ int p = tid + i*64; if(p < Pp) m = fmaxf(m, sc[p]); }
    for(int off=1; off<64; off<<=1) m = fmaxf(m, __shfl_xor(m, off, 64));
    float s = 0.0f;
    for(int i=0;i<4;i++){ int p = tid + i*64; if(p < Pp) s += fexp2((sc[p]-m)*LOG2E); }
    for(int off=1; off<64; off<<=1) s += __shfl_xor(s, off, 64);
    if(tid == 0){ red[0] = m; red[1] = frcp(s); }
  }
  __syncthreads();
  float mx = red[0], rS = red[1];
  float al_t = 0.0f;
  if(tid < Pp) al_t = fexp2((sc[tid]-mx)*LOG2E) * rS;
  __syncthreads();
  if(tid < Pp) sc[tid] = al_t;
  __syncthreads();
  float c0 = 0.f, c1 = 0.f;
  const unsigned int* fb = (const unsigned int*)(featsB + (size_t)b*Pp*Ee);
  for(int p=0;p<Pp;p++){
    float al = sc[p];
    unsigned int u = fb[(size_t)p*256 + tid];
    unsigned int lo = (u & 0xffffu) << 16, hi = u & 0xffff0000u;
    c0 += al * __builtin_bit_cast(float, lo);
    c1 += al * __builtin_bit_cast(float, hi);
  }
  unsigned int cw = ((unsigned int)f2bf(c1) << 16) | (unsigned int)f2bf(c0);
  scst4((unsigned*)ctxb + (size_t)b*256 + tid, cw);
}

// GRU gates for h-col block g (16 cols), all 128 batch rows
__device__ void gru_gates(int g, int t,
    const unsigned short* __restrict__ eseq, const unsigned short* __restrict__ ctxb,
    const unsigned short* __restrict__ WihB, const unsigned short* __restrict__ WhhB,
    const float* __restrict__ bih, const float* __restrict__ bhh,
    const float* __restrict__ hf_cur, const unsigned short* __restrict__ hb_cur,
    float* __restrict__ hf_nxt, unsigned short* __restrict__ hb_nxt, char* SM)
{
  unsigned short (*HB)[16] = (unsigned short(*)[16])SM;
  int tid = threadIdx.x;
  int w = tid>>6, l = tid&63, l16 = l&15, lk = l>>4;
  int hs = g*16 + l16;
  int m0 = w*32;
  const unsigned short* aemb = eseq + (size_t)t*Bb*Ee;
  f4 agi[2][3], agh[2][3];
  #pragma unroll
  for(int mi=0;mi<2;mi++) for(int g3=0;g3<3;g3++){ agi[mi][g3]=(f4)(0.0f); agh[mi][g3]=(f4)(0.0f); }
  for(int k0=0;k0<512;k0+=32){
    int koff = k0 + lk*8;
    bfrag ah[2], ae[2], ac[2];
    #pragma unroll
    for(int mi=0;mi<2;mi++){
      int row = m0 + mi*16 + l16;
      ah[mi] = scld_frag(hb_cur + (size_t)row*Hh + koff);
      ae[mi] = *(const bfrag*)(aemb + (size_t)row*Ee + koff);
      ac[mi] = scld_frag(ctxb + (size_t)row*Ee + koff);
    }
    #pragma unroll
    for(int g3=0;g3<3;g3++){
      int j = g3*512 + hs;
      bfrag bh_ = *(const bfrag*)(WhhB + (size_t)j*512  + koff);
      bfrag be  = *(const bfrag*)(WihB + (size_t)j*1024 + koff);
      bfrag bc  = *(const bfrag*)(WihB + (size_t)j*1024 + 512 + koff);
      #pragma unroll
      for(int mi=0;mi<2;mi++){
        agh[mi][g3] = __builtin_amdgcn_mfma_f32_16x16x32_bf16(ah[mi], bh_, agh[mi][g3], 0,0,0);
        agi[mi][g3] = __builtin_amdgcn_mfma_f32_16x16x32_bf16(ae[mi], be,  agi[mi][g3], 0,0,0);
        agi[mi][g3] = __builtin_amdgcn_mfma_f32_16x16x32_bf16(ac[mi], bc,  agi[mi][g3], 0,0,0);
      }
    }
  }
  float bir = bih[hs],      bhr = bhh[hs];
  float biz = bih[512+hs],  bhz = bhh[512+hs];
  float bin = bih[1024+hs], bhn = bhh[1024+hs];
  #pragma unroll
  for(int mi=0;mi<2;mi++){
    #pragma unroll
    for(int i=0;i<4;i++){
      int b = m0 + mi*16 + lk*4 + i;
      float r = sigm_f(agi[mi][0][i] + bir + agh[mi][0][i] + bhr);
      float z = sigm_f(agi[mi][1][i] + biz + agh[mi][1][i] + bhz);
      float n = tanh_f(agi[mi][2][i] + bin + r*(agh[mi][2][i] + bhn));
      float ho = hf_cur[(size_t)b*Hh + hs];
      float hn = (1.0f - z)*n + z*ho;
      hf_nxt[(size_t)b*Hh + hs] = hn;          // block-private across steps: plain store
      HB[b][l16] = f2bf(hn);
    }
  }
  __syncthreads();
  #pragma unroll
  for(int j2=0;j2<4;j2++){
    int wix = tid + j2*256;              // 0..1023 = 128 rows x 8 pairs
    int bb = wix >> 3, pr = wix & 7;
    unsigned u = (unsigned)HB[bb][pr*2] | ((unsigned)HB[bb][pr*2+1] << 16);
    scst4((unsigned*)(hb_nxt + (size_t)bb*Hh + g*16) + pr, u);
  }
}

// hproj = h @ Wh + bh (batched MFMA), col block g (16 a-cols), output coherent f32
__device__ void hproj_task(int g, const unsigned short* __restrict__ hbsrc,
                           const unsigned short* __restrict__ WhT,
                           const float* __restrict__ bhv, float* __restrict__ hpr)
{
  int tid = threadIdx.x;
  int w = tid>>6, l = tid&63, l16 = l&15, lk = l>>4;
  int m0 = w*32;
  int a = g*16 + l16;
  f4 acc[2]; acc[0]=(f4)(0.0f); acc[1]=(f4)(0.0f);
  for(int k0=0;k0<512;k0+=32){
    int koff = k0 + lk*8;
    bfrag bq = *(const bfrag*)(WhT + (size_t)a*Hh + koff);
    #pragma unroll
    for(int mi=0;mi<2;mi++){
      bfrag af = scld_frag(hbsrc + (size_t)(m0 + mi*16 + l16)*Hh + koff);
      acc[mi] = __builtin_amdgcn_mfma_f32_16x16x32_bf16(af, bq, acc[mi], 0,0,0);
    }
  }
  float bias = bhv[a];
  #pragma unroll
  for(int mi=0;mi<2;mi++)
    #pragma unroll
    for(int i=0;i<4;i++){
      int b = m0 + mi*16 + lk*4 + i;
      scstf(hpr + (size_t)b*Aa + a, acc[mi][i] + bias);
    }
}

// pred tile: 64 b-rows x 128 v-cols; h staged into XOR-swizzled LDS
__device__ void pred_task(int pt, int tw, const unsigned short* __restrict__ hb_cur,
                          const unsigned short* __restrict__ WoutB,
                          const float* __restrict__ bout, float* __restrict__ out,
                          char* SM)
{
  int tid = threadIdx.x;
  int vchunk = pt >> 1, mbase = (pt & 1)*64;
  // stage 64 rows x 512 bf16 into LDS (swizzle byte ^= (row&7)<<4)
  for(int j=0;j<32;j++){
    int u = tid + j*256;                  // 8192 8B-units
    int row = u >> 7, c8 = u & 127;
    unsigned long long q = scld8(hb_cur + (size_t)(mbase+row)*Hh + c8*4);
    int bo = (row<<10) + (c8<<3);
    bo ^= (row&7)<<4;
    *(unsigned long long*)(SM + bo) = q;
  }
  __syncthreads();
  int w = tid>>6, l = tid&63, l16 = l&15, lk = l>>4;
  int nb = vchunk*128 + w*32;
  f4 acc[4][2];
  #pragma unroll
  for(int mi=0;mi<4;mi++) for(int ni=0;ni<2;ni++) acc[mi][ni] = (f4)(0.0f);
  for(int k0=0;k0<512;k0+=32){
    int koff = k0 + lk*8;
    bfrag af[4], bq[2];
    #pragma unroll
    for(int mi=0;mi<4;mi++){
      int row = mi*16 + l16;
      int bo = (row<<10) + (koff<<1);
      bo ^= (row&7)<<4;
      af[mi] = *(const bfrag*)(SM + bo);
    }
    #pragma unroll
    for(int ni=0;ni<2;ni++){
      int v = nb + ni*16 + l16; if(v > Vv-1) v = Vv-1;
      bq[ni] = *(const bfrag*)(WoutB + (size_t)v*Hh + koff);
    }
    #pragma unroll
    for(int mi=0;mi<4;mi++)
      #pragma unroll
      for(int ni=0;ni<2;ni++)
        acc[mi][ni] = __builtin_amdgcn_mfma_f32_16x16x32_bf16(af[mi], bq[ni], acc[mi][ni], 0,0,0);
  }
  #pragma unroll
  for(int ni=0;ni<2;ni++){
    int v = nb + ni*16 + l16;
    if(v < Vv){
      float bias = bout[v];
      #pragma unroll
      for(int mi=0;mi<4;mi++){
        #pragma unroll
        for(int i=0;i<4;i++){
          int br = mbase + mi*16 + lk*4 + i;
          __builtin_nontemporal_store(acc[mi][ni][i] + bias,
              out + (size_t)br*TV + (size_t)tw*Vv + v);
        }
      }
    }
  }
}

// ---------------- the persistent kernel ----------------
__global__ __launch_bounds__(NTHR, 2) void k_all(
    const float* feats, const int* caps, const float* emb,
    const float* Winh, const float* binh, const float* Wino, const float* bino,
    const float* Wf, const float* bfv, const float* Wh, const float* bhv,
    const float* vatt, const float* Wih, const float* Whh,
    const float* bih, const float* bhh, const float* Wout, const float* bout,
    float* out,
    float* h_f0, float* h_f1, unsigned short* h_b0, unsigned short* h_b1,
    float* hpr, unsigned short* ctxb, unsigned short* avgB, unsigned short* eseq,
    unsigned short* WfT, unsigned short* WhT,
    unsigned short* WinhT, unsigned short* WinoT,
    unsigned short* WihB, unsigned short* WhhB,
    unsigned short* fpb, unsigned short* featsB, unsigned short* WoutB,
    unsigned* sync)
{
  __shared__ char SMEM[65536];
  const int blk = blockIdx.x, tid = threadIdx.x;
  const int gtid = blk*NTHR + tid;

  // ================= P0: casts, transposes, avg, embed =================
  cast_loop(Wih,  WihB,  (3*Hh*2*Ee)/4, gtid);
  cast_loop(Whh,  WhhB,  (3*Hh*Hh)/4,   gtid);
  cast_loop(Wout, WoutB, (Vv*Hh)/4,     gtid);
  cast_loop(feats,featsB,(Bb*Pp*Ee)/4,  gtid);
  for(int task = blk; task < 1024; task += NBLK){
    int z = task >> 8, rt = task & 255;
    int it = rt & 15, jt = rt >> 4;
    const float* S = (z==0)?Wf:(z==1)?Wh:(z==2)?Winh:Wino;
    unsigned short* D = (z==0)?WfT:(z==1)?WhT:(z==2)?WinhT:WinoT;
    tr_tile(S, D, it, jt, tid, (float(*)[33])SMEM);
  }
  if(blk < Bb){
    int b = blk;
    const float* fb = feats + (size_t)b*Pp*Ee;
    float a0=0.f, a1=0.f;
    for(int p=0;p<Pp;p++){
      float2 v = *(const float2*)(fb + (size_t)p*Ee + tid*2);
      a0 += v.x; a1 += v.y;
    }
    a0 *= (1.0f/Pp); a1 *= (1.0f/Pp);
    unsigned int pack = ((unsigned int)f2bf(a1)<<16) | (unsigned int)f2bf(a0);
    ((unsigned int*)avgB)[(size_t)b*256 + tid] = pack;
  }
  for(int task = blk; task < (Tt-1)*Bb; task += NBLK){
    int ts = task/Bb + 1, b = task%Bb;
    int cap = caps[b*Tt + (ts-1)];
    float2 v = *(const float2*)(emb + (size_t)cap*Ee + tid*2);
    unsigned int pack = ((unsigned int)f2bf(v.y)<<16) | (unsigned int)f2bf(v.x);
    ((unsigned int*)(eseq + ((size_t)ts*Bb + b)*Ee))[tid] = pack;
  }
  gbar(&sync[SYNC_CNT], &sync[SYNC_GEN]);

  // ================= P1: featproj (1568) + initproj (16) =================
  for(int task = blk; task < 1584; task += NBLK){
    int w = tid>>6, l = tid&63, l16 = l&15, lk = l>>4;
    if(task < 1568){
      int bx = task % 196, by = task / 196;
      size_t m_base = (size_t)bx*128 + (w&1)*64;
      int nb = by*64 + (w>>1)*32;
      f4 acc[4][2];
      #pragma unroll
      for(int mi=0;mi<4;mi++) for(int ni=0;ni<2;ni++) acc[mi][ni] = (f4)(0.0f);
      for(int k0=0;k0<512;k0+=32){
        int koff = k0 + lk*8;
        bfrag af[4], bq[2];
        #pragma unroll
        for(int mi=0;mi<4;mi++) af[mi] = *(const bfrag*)(featsB + (m_base+mi*16+l16)*512 + koff);
        #pragma unroll
        for(int ni=0;ni<2;ni++) bq[ni] = *(const bfrag*)(WfT + (size_t)(nb+ni*16+l16)*512 + koff);
        #pragma unroll
        for(int mi=0;mi<4;mi++)
          #pragma unroll
          for(int ni=0;ni<2;ni++)
            acc[mi][ni] = __builtin_amdgcn_mfma_f32_16x16x32_bf16(af[mi], bq[ni], acc[mi][ni], 0,0,0);
      }
      #pragma unroll
      for(int ni=0;ni<2;ni++){
        int a = nb + ni*16 + l16;
        float bias = bfv[a];
        #pragma unroll
        for(int mi=0;mi<4;mi++){
          size_t r = m_base + mi*16 + lk*4;
          #pragma unroll
          for(int i=0;i<4;i++)
            fpb[(r+i)*512 + a] = f2bf(acc[mi][ni][i] + bias);
        }
      }
    } else {
      int idx = task - 1568;
      int y = idx >> 3, xb = idx & 7;
      int m0 = (w&1)*64, nb = xb*64 + (w>>1)*32;
      const unsigned short* Wt = y ? WinoT : WinhT;
      const float* bias = y ? bino : binh;
      f4 acc[4][2];
      #pragma unroll
      for(int mi=0;mi<4;mi++) for(int ni=0;ni<2;ni++) acc[mi][ni] = (f4)(0.0f);
      for(int k0=0;k0<512;k0+=32){
        int koff = k0 + lk*8;
        bfrag af[4], bq[2];
        #pragma unroll
        for(int mi=0;mi<4;mi++) af[mi] = *(const bfrag*)(avgB + (size_t)(m0+mi*16+l16)*512 + koff);
        #pragma unroll
        for(int ni=0;ni<2;ni++) bq[ni] = *(const bfrag*)(Wt + (size_t)(nb+ni*16+l16)*512 + koff);
        #pragma unroll
        for(int mi=0;mi<4;mi++)
          #pragma unroll
          for(int ni=0;ni<2;ni++)
            acc[mi][ni] = __builtin_amdgcn_mfma_f32_16x16x32_bf16(af[mi], bq[ni], acc[mi][ni], 0,0,0);
      }
      #pragma unroll
      for(int ni=0;ni<2;ni++){
        int n = nb + ni*16 + l16;
        float bv = bias[n];
        #pragma unroll
        for(int mi=0;mi<4;mi++){
          int bb = m0 + mi*16 + lk*4;
          #pragma unroll
          for(int i=0;i<4;i++){
            float val = tanh_f(acc[mi][ni][i] + bv);
            if(y==0){ h_f0[(size_t)(bb+i)*Hh + n] = val; h_b0[(size_t)(bb+i)*Hh + n] = f2bf(val); }
            else    { eseq[(size_t)(bb+i)*Ee + n] = f2bf(val); }
          }
        }
      }
    }
  }
  gbar(&sync[SYNC_CNT], &sync[SYNC_GEN]);

  // ================= pipelined step loop (no grid barriers) =================
  float* hfv[2]          = { h_f0, h_f1 };
  unsigned short* hbv[2] = { h_b0, h_b1 };

  if(blk < 128){
    // ---- attention role ----
    for(int t=0; t<Tt; t++){
      wait_ctr(&sync[HPRD+t], 32);
      attention_task(blk, hpr, fpb, featsB, vatt, ctxb, SMEM);
      signal_ctr(&sync[CTXD+t]);
    }
  } else if(blk < 160){
    // ---- gates role ----
    int g = blk - 128;
    hproj_task(g, h_b0, WhT, bhv, hpr);
    signal_ctr(&sync[HPRD+0]);
    for(int t=0; t<Tt; t++){
      wait_ctr(&sync[CTXD+t], 128);
      if(t > 0) wait_ctr(&sync[PREDD+t-1], 314);   // hb WAR guard vs pred
      gru_gates(g, t, eseq, ctxb, WihB, WhhB, bih, bhh,
                hfv[t&1], hbv[t&1], hfv[(t+1)&1], hbv[(t+1)&1], SMEM);
      signal_ctr(&sync[HRDY+t+1]);
      if(t+1 < Tt){
        wait_ctr(&sync[HRDY+t+1], 32);
        hproj_task(g, hbv[(t+1)&1], WhT, bhv, hpr);
        signal_ctr(&sync[HPRD+t+1]);
      }
    }
  } else if(blk < 474){
    // ---- pred role ----
    int pt = blk - 160;
    for(int t=1; t<=Tt; t++){
      wait_ctr(&sync[HRDY+t], 32);
      pred_task(pt, t-1, hbv[t&1], WoutB, bout, out, SMEM);
      signal_ctr(&sync[PREDD+t-1]);
    }
  }
}

extern "C" void kernel_launch(void* const* d_in, const int* in_sizes, int n_in,
                              void* d_out, int out_size, void* d_ws, size_t ws_size,
                              hipStream_t stream)
{
  const float* feats = (const float*)d_in[0];
  const int*   caps  = (const int*)d_in[1];
  const float* emb   = (const float*)d_in[2];
  const float* Winh  = (const float*)d_in[3];
  const float* binh  = (const float*)d_in[4];
  const float* Wino  = (const float*)d_in[5];
  const float* bino  = (const float*)d_in[6];
  const float* Wf    = (const float*)d_in[7];
  const float* bfv   = (const float*)d_in[8];
  const float* Wh    = (const float*)d_in[9];
  const float* bhv   = (const float*)d_in[10];
  const float* vatt  = (const float*)d_in[11];
  const float* Wih   = (const float*)d_in[12];
  const float* Whh   = (const float*)d_in[13];
  const float* bih   = (const float*)d_in[14];
  const float* bhh   = (const float*)d_in[15];
  const float* Wout  = (const float*)d_in[16];
  const float* bout  = (const float*)d_in[17];
  float* out = (float*)d_out;

  char* ws = (char*)d_ws;
  size_t off = 0;
  auto alloc = [&](size_t bytes){
    off = (off + 255) & ~(size_t)255;
    void* p = ws + off; off += bytes; return p;
  };
  unsigned* syncp = (unsigned*)alloc(1024);
  float* h_f0 = (float*)alloc((size_t)Bb*Hh*4);
  float* h_f1 = (float*)alloc((size_t)Bb*Hh*4);
  unsigned short* h_b0 = (unsigned short*)alloc((size_t)Bb*Hh*2);
  unsigned short* h_b1 = (unsigned short*)alloc((size_t)Bb*Hh*2);
  float* hpr = (float*)alloc((size_t)Bb*Aa*4);
  unsigned short* ctxb  = (unsigned short*)alloc((size_t)Bb*Ee*2);
  unsigned short* avgB  = (unsigned short*)alloc((size_t)Bb*Ee*2);
  unsigned short* eseq  = (unsigned short*)alloc((size_t)Tt*Bb*Ee*2);
  unsigned short* WfT   = (unsigned short*)alloc((size_t)Ee*Aa*2);
  unsigned short* WhT   = (unsigned short*)alloc((size_t)Hh*Aa*2);
  unsigned short* WinhT = (unsigned short*)alloc((size_t)Ee*Hh*2);
  unsigned short* WinoT = (unsigned short*)alloc((size_t)Ee*Hh*2);
  unsigned short* WihB  = (unsigned short*)alloc((size_t)3*Hh*2*Ee*2);
  unsigned short* WhhB  = (unsigned short*)alloc((size_t)3*Hh*Hh*2);
  unsigned short* fpb   = (unsigned short*)alloc((size_t)Bb*Pp*Aa*2);
  unsigned short* featsB= (unsigned short*)alloc((size_t)Bb*Pp*Ee*2);
  unsigned short* WoutB = (unsigned short*)alloc((size_t)Vv*Hh*2);
  if(ws_size < off) return;   // diagnostic no-op

  k_zero<<<1, 256, 0, stream>>>(syncp);
  k_all<<<NBLK, NTHR, 0, stream>>>(
      feats, caps, emb, Winh, binh, Wino, bino, Wf, bfv, Wh, bhv, vatt,
      Wih, Whh, bih, bhh, Wout, bout, out,
      h_f0, h_f1, h_b0, h_b1, hpr, ctxb, avgB, eseq,
      WfT, WhT, WinhT, WinoT, WihB, WhhB, fpb, featsB, WoutB, syncp);
}

// Round 6
// 1638.633 us; speedup vs baseline: 1.8758x; 1.3999x over previous
//
#include <hip/hip_runtime.h>

#define Bb 128
#define Tt 24
#define Ee 512
#define Hh 512
#define Aa 512
#define Vv 20000
#define Pp 196
#define TV (Tt*Vv)
#define NBLK 512
#define NTHR 256
#define GT (NBLK*NTHR)

typedef __attribute__((ext_vector_type(8))) short bfrag;           // 8 bf16
typedef __attribute__((ext_vector_type(4))) float f4;              // MFMA acc
typedef __attribute__((ext_vector_type(4))) unsigned short us4;    // 4 bf16
typedef __attribute__((ext_vector_type(2))) unsigned long long u64x2;

#define MFMA16(a,b,c) __builtin_amdgcn_mfma_f32_16x16x32_bf16(a,b,c,0,0,0)

__device__ __forceinline__ unsigned short f2bf(float f){
  unsigned int x = __builtin_bit_cast(unsigned int, f);
  x += 0x7fffu + ((x >> 16) & 1u);   // RTNE
  return (unsigned short)(x >> 16);
}
__device__ __forceinline__ float bfu2f(unsigned short u){
  unsigned int x = ((unsigned int)u) << 16;
  return __builtin_bit_cast(float, x);
}
#define LOG2E 1.442695041f
__device__ __forceinline__ float fexp2(float x){ return __builtin_amdgcn_exp2f(x); }
__device__ __forceinline__ float frcp (float x){ return __builtin_amdgcn_rcpf(x); }
__device__ __forceinline__ float tanh_f(float x){ return 1.0f - 2.0f*frcp(1.0f + fexp2((2.0f*LOG2E)*x)); }
__device__ __forceinline__ float sigm_f(float x){ return frcp(1.0f + fexp2(-LOG2E*x)); }

// ---- device-coherent (cache-bypass) access helpers ----
__device__ __forceinline__ unsigned long long scld8(const void* p){
  return __hip_atomic_load((const unsigned long long*)p, __ATOMIC_RELAXED, __HIP_MEMORY_SCOPE_AGENT);
}
__device__ __forceinline__ unsigned scld4(const unsigned* p){
  return __hip_atomic_load(p, __ATOMIC_RELAXED, __HIP_MEMORY_SCOPE_AGENT);
}
__device__ __forceinline__ bfrag scld_frag(const unsigned short* p){
  u64x2 v;
  v.x = scld8(p);
  v.y = scld8(p + 4);
  return __builtin_bit_cast(bfrag, v);
}
__device__ __forceinline__ void scst4(unsigned* p, unsigned v){
  __hip_atomic_store(p, v, __ATOMIC_RELAXED, __HIP_MEMORY_SCOPE_AGENT);
}
__device__ __forceinline__ void scstf(float* p, float v){
  __hip_atomic_store(p, v, __ATOMIC_RELAXED, __HIP_MEMORY_SCOPE_AGENT);
}

// ---- per-block flag signal / parallel-poll (no same-address storms) ----
// flag lines are 64B apart; value = generation (monotone), no reset needed.
__device__ __forceinline__ void set_flag(unsigned* line, unsigned v){
  asm volatile("s_waitcnt vmcnt(0)" ::: "memory");
  __syncthreads();
  if(threadIdx.x == 0) scst4(line, v);
}
__device__ __forceinline__ void poll_flags(const unsigned* base, int n, unsigned tgt){
  int tid = threadIdx.x;
  for(;;){
    int ok = (tid < n) ? (scld4(base + tid*16) >= tgt) : 1;
    if(__syncthreads_count(ok) == NTHR) break;
    __builtin_amdgcn_s_sleep(2);
  }
  asm volatile("" ::: "memory");
}

// ---- prep grid barrier: 32 split counters + leader-published generation ----
__device__ __forceinline__ void gbar2(unsigned* sync, unsigned phase){
  __syncthreads();
  int tid = threadIdx.x, blk = blockIdx.x;
  if(tid == 0)
    (void)__hip_atomic_fetch_add(sync + (blk & 31)*16, 1u,
                                 __ATOMIC_RELEASE, __HIP_MEMORY_SCOPE_AGENT);
  if(blk == 0){
    for(;;){
      int ok = (tid < 32) ? (scld4(sync + tid*16) >= phase*16u) : 1;
      if(__syncthreads_count(ok) == NTHR) break;
      __builtin_amdgcn_s_sleep(2);
    }
    if(tid == 0) scst4(sync + 32*16, phase);
  }
  if(tid == 0){
    while(scld4(sync + 32*16) < phase) __builtin_amdgcn_s_sleep(2);
    (void)__hip_atomic_load(sync + 32*16, __ATOMIC_ACQUIRE, __HIP_MEMORY_SCOPE_AGENT);
  }
  __syncthreads();
}

__global__ void k_zero(unsigned* s){
  int i = blockIdx.x*256 + threadIdx.x;
  s[i] = 0u;          // grid sized to cover whole sync region
}

// ---------------- prep helpers ----------------
__device__ __forceinline__ void cast_loop(const float* __restrict__ s,
                                          unsigned short* __restrict__ d,
                                          int n4, int gtid){
  for(int i = gtid; i < n4; i += GT){
    float4 v = ((const float4*)s)[i];
    us4 o; o[0]=f2bf(v.x); o[1]=f2bf(v.y); o[2]=f2bf(v.z); o[3]=f2bf(v.w);
    ((us4*)d)[i] = o;
  }
}
__device__ __forceinline__ void tr_tile(const float* __restrict__ S,
                                        unsigned short* __restrict__ D,
                                        int it, int jt, int tid, float (*T)[33]){
  int er = tid>>3, c4 = (tid&7)*4;
  float4 v = *(const float4*)(S + (size_t)(jt*32+er)*512 + it*32 + c4);
  T[er][c4+0]=v.x; T[er][c4+1]=v.y; T[er][c4+2]=v.z; T[er][c4+3]=v.w;
  __syncthreads();
  us4 o;
  o[0]=f2bf(T[c4+0][er]); o[1]=f2bf(T[c4+1][er]);
  o[2]=f2bf(T[c4+2][er]); o[3]=f2bf(T[c4+3][er]);
  *(us4*)(D + (size_t)(it*32+er)*512 + jt*32 + c4) = o;
  __syncthreads();
}

// ---------------- step-loop tasks ----------------

__device__ void attention_task(int b, const float* __restrict__ hpr,
                               const unsigned short* __restrict__ fpb,
                               const unsigned short* __restrict__ featsB,
                               const float* __restrict__ vatt,
                               unsigned short* __restrict__ ctxb, char* SM)
{
  float* hp  = (float*)SM;        // 512, permuted hp[(a&31)*16 + (a>>5)]
  float* vp  = hp + 512;
  float* sc  = vp + 512;
  float* red = sc + 200;
  int tid = threadIdx.x;
  {
    unsigned long long q = scld8(hpr + (size_t)b*Aa + tid*2);
    float2 hv = __builtin_bit_cast(float2, q);
    float2 vv = *(const float2*)(vatt + tid*2);
    int a0 = tid*2, a1 = tid*2+1;
    hp[((a0&31)<<4)+(a0>>5)] = hv.x;
    hp[((a1&31)<<4)+(a1>>5)] = hv.y;
    vp[((a0&31)<<4)+(a0>>5)] = vv.x;
    vp[((a1&31)<<4)+(a1>>5)] = vv.y;
  }
  __syncthreads();
  int grp = tid >> 4, gl = tid & 15;
  for(int pass=0; pass<13; pass++){
    int p = pass*16 + grp;
    float acc = 0.0f;
    if(p < Pp){
      const unsigned short* fr = fpb + ((size_t)b*Pp + p)*Aa + gl*32;
      #pragma unroll
      for(int j=0;j<32;j+=8){
        bfrag fv = *(const bfrag*)(fr + j);
        #pragma unroll
        for(int q=0;q<8;q++){
          int idx = ((j+q)<<4) + gl;
          float x = bfu2f((unsigned short)fv[q]) + hp[idx];
          acc += tanh_f(x) * vp[idx];
        }
      }
    }
    acc += __shfl_xor(acc, 1, 64);
    acc += __shfl_xor(acc, 2, 64);
    acc += __shfl_xor(acc, 4, 64);
    acc += __shfl_xor(acc, 8, 64);
    if(p < Pp && gl == 0) sc[p] = acc;
  }
  __syncthreads();
  if(tid < 64){
    float m = -1e30f;
    for(int i=0;i<4;i++){ int p = tid + i*64; if(p < Pp) m = fmaxf(m, sc[p]); }
    for(int off=1; off<64; off<<=1) m = fmaxf(m, __shfl_xor(m, off, 64));
    float s = 0.0f;
    for(int i=0;i<4;i++){ int p = tid + i*64; if(p < Pp) s += fexp2((sc[p]-m)*LOG2E); }
    for(int off=1; off<64; off<<=1) s += __shfl_xor(s, off, 64);
    if(tid == 0){ red[0] = m; red[1] = frcp(s); }
  }
  __syncthreads();
  float mx = red[0], rS = red[1];
  float al_t = 0.0f;
  if(tid < Pp) al_t = fexp2((sc[tid]-mx)*LOG2E) * rS;
  __syncthreads();
  if(tid < Pp) sc[tid] = al_t;
  __syncthreads();
  float c0 = 0.f, c1 = 0.f;
  const unsigned int* fb = (const unsigned int*)(featsB + (size_t)b*Pp*Ee);
  for(int p=0;p<Pp;p++){
    float al = sc[p];
    unsigned int u = fb[(size_t)p*256 + tid];
    unsigned int lo = (u & 0xffffu) << 16, hi = u & 0xffff0000u;
    c0 += al * __builtin_bit_cast(float, lo);
    c1 += al * __builtin_bit_cast(float, hi);
  }
  unsigned int cw = ((unsigned int)f2bf(c1) << 16) | (unsigned int)f2bf(c0);
  scst4((unsigned*)ctxb + (size_t)b*256 + tid, cw);
}

// gates phase A: agh = h@Whh^T, agi = emb@Wih_emb^T  (no ctx dependency)
__device__ void gates_phaseA(int g, const unsigned short* __restrict__ hbs,
                             const unsigned short* __restrict__ aemb,
                             const unsigned short* __restrict__ WihB,
                             const unsigned short* __restrict__ WhhB,
                             f4 (&agh)[2][3], f4 (&agi)[2][3])
{
  int tid = threadIdx.x;
  int w = tid>>6, l = tid&63, l16 = l&15, lk = l>>4;
  int hs = g*16 + l16, m0 = w*32;
  #pragma unroll
  for(int mi=0;mi<2;mi++) for(int q=0;q<3;q++){ agh[mi][q]=(f4)(0.f); agi[mi][q]=(f4)(0.f); }
  bfrag ah0 = scld_frag(hbs + (size_t)(m0+l16)*Hh + lk*8);
  bfrag ah1 = scld_frag(hbs + (size_t)(m0+16+l16)*Hh + lk*8);
  for(int k0=0;k0<512;k0+=32){
    int koff = k0 + lk*8;
    bfrag nh0 = ah0, nh1 = ah1;
    if(k0+32 < 512){
      nh0 = scld_frag(hbs + (size_t)(m0+l16)*Hh + koff + 32);
      nh1 = scld_frag(hbs + (size_t)(m0+16+l16)*Hh + koff + 32);
    }
    bfrag ae0 = *(const bfrag*)(aemb + (size_t)(m0+l16)*Ee + koff);
    bfrag ae1 = *(const bfrag*)(aemb + (size_t)(m0+16+l16)*Ee + koff);
    #pragma unroll
    for(int q=0;q<3;q++){
      int j = q*512 + hs;
      bfrag bh_ = *(const bfrag*)(WhhB + (size_t)j*512  + koff);
      bfrag be  = *(const bfrag*)(WihB + (size_t)j*1024 + koff);
      agh[0][q] = MFMA16(ah0, bh_, agh[0][q]);
      agh[1][q] = MFMA16(ah1, bh_, agh[1][q]);
      agi[0][q] = MFMA16(ae0, be,  agi[0][q]);
      agi[1][q] = MFMA16(ae1, be,  agi[1][q]);
    }
    ah0 = nh0; ah1 = nh1;
  }
}

// gates phase B: agi += ctx@Wih_ctx^T, then gate math + h_new write
__device__ void gates_phaseB(int g, const unsigned short* __restrict__ ctxb,
                             const unsigned short* __restrict__ WihB,
                             const float* __restrict__ bih, const float* __restrict__ bhh,
                             const float* __restrict__ hf_cur, float* __restrict__ hf_nxt,
                             unsigned short* __restrict__ hb_nxt,
                             f4 (&agh)[2][3], f4 (&agi)[2][3], char* SM)
{
  unsigned short (*HB)[16] = (unsigned short(*)[16])SM;
  int tid = threadIdx.x;
  int w = tid>>6, l = tid&63, l16 = l&15, lk = l>>4;
  int hs = g*16 + l16, m0 = w*32;
  bfrag ac0 = scld_frag(ctxb + (size_t)(m0+l16)*Ee + lk*8);
  bfrag ac1 = scld_frag(ctxb + (size_t)(m0+16+l16)*Ee + lk*8);
  for(int k0=0;k0<512;k0+=32){
    int koff = k0 + lk*8;
    bfrag nc0 = ac0, nc1 = ac1;
    if(k0+32 < 512){
      nc0 = scld_frag(ctxb + (size_t)(m0+l16)*Ee + koff + 32);
      nc1 = scld_frag(ctxb + (size_t)(m0+16+l16)*Ee + koff + 32);
    }
    #pragma unroll
    for(int q=0;q<3;q++){
      int j = q*512 + hs;
      bfrag bc = *(const bfrag*)(WihB + (size_t)j*1024 + 512 + koff);
      agi[0][q] = MFMA16(ac0, bc, agi[0][q]);
      agi[1][q] = MFMA16(ac1, bc, agi[1][q]);
    }
    ac0 = nc0; ac1 = nc1;
  }
  float bir = bih[hs],      bhr = bhh[hs];
  float biz = bih[512+hs],  bhz = bhh[512+hs];
  float bin = bih[1024+hs], bhn = bhh[1024+hs];
  #pragma unroll
  for(int mi=0;mi<2;mi++){
    #pragma unroll
    for(int i=0;i<4;i++){
      int b = m0 + mi*16 + lk*4 + i;
      float r = sigm_f(agi[mi][0][i] + bir + agh[mi][0][i] + bhr);
      float z = sigm_f(agi[mi][1][i] + biz + agh[mi][1][i] + bhz);
      float n = tanh_f(agi[mi][2][i] + bin + r*(agh[mi][2][i] + bhn));
      float ho = hf_cur[(size_t)b*Hh + hs];
      float hn = (1.0f - z)*n + z*ho;
      hf_nxt[(size_t)b*Hh + hs] = hn;      // block-private across steps
      HB[b][l16] = f2bf(hn);
    }
  }
  __syncthreads();
  #pragma unroll
  for(int j2=0;j2<4;j2++){
    int wix = tid + j2*256;
    int bb = wix >> 3, pr = wix & 7;
    unsigned u = (unsigned)HB[bb][pr*2] | ((unsigned)HB[bb][pr*2+1] << 16);
    scst4((unsigned*)(hb_nxt + (size_t)bb*Hh + g*16) + pr, u);
  }
}

// hproj = h @ Wh + bh, col block g (16 a-cols)
__device__ void hproj_task(int g, const unsigned short* __restrict__ hbsrc,
                           const unsigned short* __restrict__ WhT,
                           const float* __restrict__ bhv, float* __restrict__ hpr)
{
  int tid = threadIdx.x;
  int w = tid>>6, l = tid&63, l16 = l&15, lk = l>>4;
  int m0 = w*32;
  int a = g*16 + l16;
  f4 acc[2]; acc[0]=(f4)(0.0f); acc[1]=(f4)(0.0f);
  bfrag af0 = scld_frag(hbsrc + (size_t)(m0+l16)*Hh + lk*8);
  bfrag af1 = scld_frag(hbsrc + (size_t)(m0+16+l16)*Hh + lk*8);
  for(int k0=0;k0<512;k0+=32){
    int koff = k0 + lk*8;
    bfrag n0 = af0, n1 = af1;
    if(k0+32 < 512){
      n0 = scld_frag(hbsrc + (size_t)(m0+l16)*Hh + koff + 32);
      n1 = scld_frag(hbsrc + (size_t)(m0+16+l16)*Hh + koff + 32);
    }
    bfrag bq = *(const bfrag*)(WhT + (size_t)a*Hh + koff);
    acc[0] = MFMA16(af0, bq, acc[0]);
    acc[1] = MFMA16(af1, bq, acc[1]);
    af0 = n0; af1 = n1;
  }
  float bias = bhv[a];
  #pragma unroll
  for(int mi=0;mi<2;mi++)
    #pragma unroll
    for(int i=0;i<4;i++){
      int b = m0 + mi*16 + lk*4 + i;
      scstf(hpr + (size_t)b*Aa + a, acc[mi][i] + bias);
    }
}

// pred tile: 64 b-rows x 128 v-cols; h staged into XOR-swizzled LDS
__device__ void pred_task(int pt, int tw, const unsigned short* __restrict__ hb_cur,
                          const unsigned short* __restrict__ WoutB,
                          const float* __restrict__ bout, float* __restrict__ out,
                          char* SM)
{
  int tid = threadIdx.x;
  int vchunk = pt >> 1, mbase = (pt & 1)*64;
  for(int j=0;j<32;j++){
    int u = tid + j*256;
    int row = u >> 7, c8 = u & 127;
    unsigned long long q = scld8(hb_cur + (size_t)(mbase+row)*Hh + c8*4);
    int bo = (row<<10) + (c8<<3);
    bo ^= (row&7)<<4;
    *(unsigned long long*)(SM + bo) = q;
  }
  __syncthreads();
  int w = tid>>6, l = tid&63, l16 = l&15, lk = l>>4;
  int nb = vchunk*128 + w*32;
  f4 acc[4][2];
  #pragma unroll
  for(int mi=0;mi<4;mi++) for(int ni=0;ni<2;ni++) acc[mi][ni] = (f4)(0.0f);
  for(int k0=0;k0<512;k0+=32){
    int koff = k0 + lk*8;
    bfrag af[4], bq[2];
    #pragma unroll
    for(int mi=0;mi<4;mi++){
      int row = mi*16 + l16;
      int bo = (row<<10) + (koff<<1);
      bo ^= (row&7)<<4;
      af[mi] = *(const bfrag*)(SM + bo);
    }
    #pragma unroll
    for(int ni=0;ni<2;ni++){
      int v = nb + ni*16 + l16; if(v > Vv-1) v = Vv-1;
      bq[ni] = *(const bfrag*)(WoutB + (size_t)v*Hh + koff);
    }
    #pragma unroll
    for(int mi=0;mi<4;mi++)
      #pragma unroll
      for(int ni=0;ni<2;ni++)
        acc[mi][ni] = MFMA16(af[mi], bq[ni], acc[mi][ni]);
  }
  #pragma unroll
  for(int ni=0;ni<2;ni++){
    int v = nb + ni*16 + l16;
    if(v < Vv){
      float bias = bout[v];
      #pragma unroll
      for(int mi=0;mi<4;mi++){
        #pragma unroll
        for(int i=0;i<4;i++){
          int br = mbase + mi*16 + lk*4 + i;
          __builtin_nontemporal_store(acc[mi][ni][i] + bias,
              out + (size_t)br*TV + (size_t)tw*Vv + v);
        }
      }
    }
  }
  __syncthreads();
}

// ---------------- the persistent kernel ----------------
// sync layout (64B lines): [0..31] gbar ctrs, [32] gen,
// [33..160] flagsA (attn b), [161..192] flagsH (gates g), [193..224] flagsP (gates g)
__global__ __launch_bounds__(NTHR, 2) void k_all(
    const float* feats, const int* caps, const float* emb,
    const float* Winh, const float* binh, const float* Wino, const float* bino,
    const float* Wf, const float* bfv, const float* Wh, const float* bhv,
    const float* vatt, const float* Wih, const float* Whh,
    const float* bih, const float* bhh, const float* Wout, const float* bout,
    float* out,
    float* hfR, unsigned short* hbR, float* hpr,
    unsigned short* ctxR, unsigned short* avgB, unsigned short* eseq,
    unsigned short* WfT, unsigned short* WhT,
    unsigned short* WinhT, unsigned short* WinoT,
    unsigned short* WihB, unsigned short* WhhB,
    unsigned short* fpb, unsigned short* featsB, unsigned short* WoutB,
    unsigned* sync)
{
  __shared__ char SMEM[65536];
  const int blk = blockIdx.x, tid = threadIdx.x;
  const int gtid = blk*NTHR + tid;
  unsigned* flagsA = sync + 33*16;
  unsigned* flagsH = sync + 161*16;
  unsigned* flagsP = sync + 193*16;
  float* h_f0 = hfR;                       // ring slot 0
  unsigned short* h_b0 = hbR;              // ring slot 0

  // ================= P0: casts, transposes, avg, embed =================
  cast_loop(Wih,  WihB,  (3*Hh*2*Ee)/4, gtid);
  cast_loop(Whh,  WhhB,  (3*Hh*Hh)/4,   gtid);
  cast_loop(Wout, WoutB, (Vv*Hh)/4,     gtid);
  cast_loop(feats,featsB,(Bb*Pp*Ee)/4,  gtid);
  for(int task = blk; task < 1024; task += NBLK){
    int z = task >> 8, rt = task & 255;
    int it = rt & 15, jt = rt >> 4;
    const float* S = (z==0)?Wf:(z==1)?Wh:(z==2)?Winh:Wino;
    unsigned short* D = (z==0)?WfT:(z==1)?WhT:(z==2)?WinhT:WinoT;
    tr_tile(S, D, it, jt, tid, (float(*)[33])SMEM);
  }
  if(blk < Bb){
    int b = blk;
    const float* fb = feats + (size_t)b*Pp*Ee;
    float a0=0.f, a1=0.f;
    for(int p=0;p<Pp;p++){
      float2 v = *(const float2*)(fb + (size_t)p*Ee + tid*2);
      a0 += v.x; a1 += v.y;
    }
    a0 *= (1.0f/Pp); a1 *= (1.0f/Pp);
    unsigned int pack = ((unsigned int)f2bf(a1)<<16) | (unsigned int)f2bf(a0);
    ((unsigned int*)avgB)[(size_t)b*256 + tid] = pack;
  }
  for(int task = blk; task < (Tt-1)*Bb; task += NBLK){
    int ts = task/Bb + 1, b = task%Bb;
    int cap = caps[b*Tt + (ts-1)];
    float2 v = *(const float2*)(emb + (size_t)cap*Ee + tid*2);
    unsigned int pack = ((unsigned int)f2bf(v.y)<<16) | (unsigned int)f2bf(v.x);
    ((unsigned int*)(eseq + ((size_t)ts*Bb + b)*Ee))[tid] = pack;
  }
  gbar2(sync, 1);

  // ================= P1: featproj (1568) + initproj (16) =================
  for(int task = blk; task < 1584; task += NBLK){
    int w = tid>>6, l = tid&63, l16 = l&15, lk = l>>4;
    if(task < 1568){
      int bx = task % 196, by = task / 196;
      size_t m_base = (size_t)bx*128 + (w&1)*64;
      int nb = by*64 + (w>>1)*32;
      f4 acc[4][2];
      #pragma unroll
      for(int mi=0;mi<4;mi++) for(int ni=0;ni<2;ni++) acc[mi][ni] = (f4)(0.0f);
      for(int k0=0;k0<512;k0+=32){
        int koff = k0 + lk*8;
        bfrag af[4], bq[2];
        #pragma unroll
        for(int mi=0;mi<4;mi++) af[mi] = *(const bfrag*)(featsB + (m_base+mi*16+l16)*512 + koff);
        #pragma unroll
        for(int ni=0;ni<2;ni++) bq[ni] = *(const bfrag*)(WfT + (size_t)(nb+ni*16+l16)*512 + koff);
        #pragma unroll
        for(int mi=0;mi<4;mi++)
          #pragma unroll
          for(int ni=0;ni<2;ni++)
            acc[mi][ni] = MFMA16(af[mi], bq[ni], acc[mi][ni]);
      }
      #pragma unroll
      for(int ni=0;ni<2;ni++){
        int a = nb + ni*16 + l16;
        float bias = bfv[a];
        #pragma unroll
        for(int mi=0;mi<4;mi++){
          size_t r = m_base + mi*16 + lk*4;
          #pragma unroll
          for(int i=0;i<4;i++)
            fpb[(r+i)*512 + a] = f2bf(acc[mi][ni][i] + bias);
        }
      }
    } else {
      int idx = task - 1568;
      int y = idx >> 3, xb = idx & 7;
      int m0 = (w&1)*64, nb = xb*64 + (w>>1)*32;
      const unsigned short* Wt = y ? WinoT : WinhT;
      const float* bias = y ? bino : binh;
      f4 acc[4][2];
      #pragma unroll
      for(int mi=0;mi<4;mi++) for(int ni=0;ni<2;ni++) acc[mi][ni] = (f4)(0.0f);
      for(int k0=0;k0<512;k0+=32){
        int koff = k0 + lk*8;
        bfrag af[4], bq[2];
        #pragma unroll
        for(int mi=0;mi<4;mi++) af[mi] = *(const bfrag*)(avgB + (size_t)(m0+mi*16+l16)*512 + koff);
        #pragma unroll
        for(int ni=0;ni<2;ni++) bq[ni] = *(const bfrag*)(Wt + (size_t)(nb+ni*16+l16)*512 + koff);
        #pragma unroll
        for(int mi=0;mi<4;mi++)
          #pragma unroll
          for(int ni=0;ni<2;ni++)
            acc[mi][ni] = MFMA16(af[mi], bq[ni], acc[mi][ni]);
      }
      #pragma unroll
      for(int ni=0;ni<2;ni++){
        int n = nb + ni*16 + l16;
        float bv = bias[n];
        #pragma unroll
        for(int mi=0;mi<4;mi++){
          int bb = m0 + mi*16 + lk*4;
          #pragma unroll
          for(int i=0;i<4;i++){
            float val = tanh_f(acc[mi][ni][i] + bv);
            if(y==0){ h_f0[(size_t)(bb+i)*Hh + n] = val; h_b0[(size_t)(bb+i)*Hh + n] = f2bf(val); }
            else    { eseq[(size_t)(bb+i)*Ee + n] = f2bf(val); }
          }
        }
      }
    }
  }
  gbar2(sync, 2);

  // ================= flag-pipelined step loop =================
  // role map: xcd = blk&7 (assumed XCD), slot = blk>>3 (64 per XCD)
  int xcd = blk & 7, slot = blk >> 3;

  if(slot < 16){
    // ---- attention role (16 per XCD) ----
    int b = xcd*16 + slot;
    for(int t=0; t<Tt; t++){
      poll_flags(flagsP, 32, (unsigned)(t+1));
      attention_task(b, hpr + (size_t)(t&1)*Bb*Aa, fpb, featsB, vatt,
                     ctxR + (size_t)(t&1)*Bb*Ee, SMEM);
      set_flag(flagsA + b*16, (unsigned)(t+1));
    }
  } else if(slot < 20){
    // ---- gates role (4 per XCD) ----
    int g = xcd*4 + (slot-16);
    f4 agh[2][3], agi[2][3];
    hproj_task(g, hbR, WhT, bhv, hpr);                   // h_0 -> hpr slot 0
    set_flag(flagsP + g*16, 1u);
    gates_phaseA(g, hbR, eseq, WihB, WhhB, agh, agi);    // t = 0 partials
    for(int t=0; t<Tt; t++){
      poll_flags(flagsA, 128, (unsigned)(t+1));
      gates_phaseB(g, ctxR + (size_t)(t&1)*Bb*Ee, WihB, bih, bhh,
                   hfR + (size_t)(t&1)*Bb*Hh, hfR + (size_t)((t+1)&1)*Bb*Hh,
                   hbR + (size_t)(t+1)*Bb*Hh, agh, agi, SMEM);
      set_flag(flagsH + g*16, (unsigned)(t+1));
      if(t+1 < Tt){
        poll_flags(flagsH, 32, (unsigned)(t+1));
        hproj_task(g, hbR + (size_t)(t+1)*Bb*Hh, WhT, bhv,
                   hpr + (size_t)((t+1)&1)*Bb*Aa);
        set_flag(flagsP + g*16, (unsigned)(t+2));
        gates_phaseA(g, hbR + (size_t)(t+1)*Bb*Hh, eseq + (size_t)(t+1)*Bb*Ee,
                     WihB, WhhB, agh, agi);
      }
    }
  } else if(slot < 60){
    // ---- pred role (40 per XCD, contiguous pt -> L2-resident Wout slice) ----
    int pt = xcd*40 + (slot-20);
    if(pt < 314){
      for(int t=1; t<=Tt; t++){
        poll_flags(flagsH, 32, (unsigned)t);
        pred_task(pt, t-1, hbR + (size_t)t*Bb*Hh, WoutB, bout, out, SMEM);
      }
    }
  }
}

extern "C" void kernel_launch(void* const* d_in, const int* in_sizes, int n_in,
                              void* d_out, int out_size, void* d_ws, size_t ws_size,
                              hipStream_t stream)
{
  const float* feats = (const float*)d_in[0];
  const int*   caps  = (const int*)d_in[1];
  const float* emb   = (const float*)d_in[2];
  const float* Winh  = (const float*)d_in[3];
  const float* binh  = (const float*)d_in[4];
  const float* Wino  = (const float*)d_in[5];
  const float* bino  = (const float*)d_in[6];
  const float* Wf    = (const float*)d_in[7];
  const float* bfv   = (const float*)d_in[8];
  const float* Wh    = (const float*)d_in[9];
  const float* bhv   = (const float*)d_in[10];
  const float* vatt  = (const float*)d_in[11];
  const float* Wih   = (const float*)d_in[12];
  const float* Whh   = (const float*)d_in[13];
  const float* bih   = (const float*)d_in[14];
  const float* bhh   = (const float*)d_in[15];
  const float* Wout  = (const float*)d_in[16];
  const float* bout  = (const float*)d_in[17];
  float* out = (float*)d_out;

  char* ws = (char*)d_ws;
  size_t off = 0;
  auto alloc = [&](size_t bytes){
    off = (off + 255) & ~(size_t)255;
    void* p = ws + off; off += bytes; return p;
  };
  unsigned* syncp = (unsigned*)alloc(16384);
  float* hfR = (float*)alloc((size_t)2*Bb*Hh*4);                 // hf ring (2)
  unsigned short* hbR = (unsigned short*)alloc((size_t)(Tt+1)*Bb*Hh*2);  // hb ring (25)
  float* hpr = (float*)alloc((size_t)2*Bb*Aa*4);                 // hproj ring (2)
  unsigned short* ctxR  = (unsigned short*)alloc((size_t)2*Bb*Ee*2);     // ctx ring (2)
  unsigned short* avgB  = (unsigned short*)alloc((size_t)Bb*Ee*2);
  unsigned short* eseq  = (unsigned short*)alloc((size_t)Tt*Bb*Ee*2);
  unsigned short* WfT   = (unsigned short*)alloc((size_t)Ee*Aa*2);
  unsigned short* WhT   = (unsigned short*)alloc((size_t)Hh*Aa*2);
  unsigned short* WinhT = (unsigned short*)alloc((size_t)Ee*Hh*2);
  unsigned short* WinoT = (unsigned short*)alloc((size_t)Ee*Hh*2);
  unsigned short* WihB  = (unsigned short*)alloc((size_t)3*Hh*2*Ee*2);
  unsigned short* WhhB  = (unsigned short*)alloc((size_t)3*Hh*Hh*2);
  unsigned short* fpb   = (unsigned short*)alloc((size_t)Bb*Pp*Aa*2);
  unsigned short* featsB= (unsigned short*)alloc((size_t)Bb*Pp*Ee*2);
  unsigned short* WoutB = (unsigned short*)alloc((size_t)Vv*Hh*2);
  if(ws_size < off) return;   // diagnostic no-op

  k_zero<<<16, 256, 0, stream>>>(syncp);   // zeros whole 16 KB sync region
  k_all<<<NBLK, NTHR, 0, stream>>>(
      feats, caps, emb, Winh, binh, Wino, bino, Wf, bfv, Wh, bhv, vatt,
      Wih, Whh, bih, bhh, Wout, bout, out,
      hfR, hbR, hpr, ctxR, avgB, eseq,
      WfT, WhT, WinhT, WinoT, WihB, WhhB, fpb, featsB, WoutB, syncp);
}